// Round 1
// baseline (3437.896 us; speedup 1.0000x reference)
//
#include <hip/hip_runtime.h>

#define D_MODEL 1024
#define SEQ     1024
#define BATCH   4
#define NHEAD   16
#define HDIM    64
#define FF_DIM  4096
#define NLAYER  8
#define VOCAB   32000
#define ROWS    (BATCH*SEQ)
#define LN_EPS  1e-5f

typedef __attribute__((ext_vector_type(4))) float   f32x4;
typedef __attribute__((ext_vector_type(8))) unsigned short u16x8;
typedef __attribute__((ext_vector_type(8))) __bf16  bf16x8;

__device__ __forceinline__ unsigned short f2bf(float f) {
    unsigned int u = __builtin_bit_cast(unsigned int, f);
    u += 0x7FFFu + ((u >> 16) & 1u);   // RNE
    return (unsigned short)(u >> 16);
}

__device__ __forceinline__ f32x4 mfma32(u16x8 a, u16x8 b, f32x4 c) {
    return __builtin_amdgcn_mfma_f32_16x16x32_bf16(
        __builtin_bit_cast(bf16x8, a), __builtin_bit_cast(bf16x8, b), c, 0, 0, 0);
}

// ---------------- embed: x = emb[tok] + pos ----------------
__global__ __launch_bounds__(256) void embed_k(
    const int* __restrict__ tok, const float* __restrict__ emb,
    const float* __restrict__ pos, float* __restrict__ x,
    unsigned short* __restrict__ xb)
{
    int bs = blockIdx.x;
    int s  = bs & (SEQ - 1);
    int tk = tok[bs];
    int c  = threadIdx.x * 4;
    float4 e = *(const float4*)(emb + (size_t)tk * D_MODEL + c);
    float4 p = *(const float4*)(pos + (size_t)s * D_MODEL + c);
    float y0 = e.x + p.x, y1 = e.y + p.y, y2 = e.z + p.z, y3 = e.w + p.w;
    size_t base = (size_t)bs * D_MODEL + c;
    *(float4*)(x + base) = make_float4(y0, y1, y2, y3);
    unsigned long long pk = (unsigned long long)f2bf(y0)
        | ((unsigned long long)f2bf(y1) << 16)
        | ((unsigned long long)f2bf(y2) << 32)
        | ((unsigned long long)f2bf(y3) << 48);
    *(unsigned long long*)(xb + base) = pk;
}

// ---------------- cast fp32 -> bf16 (emb for tied head) ----------------
__global__ __launch_bounds__(256) void cast_bf(
    const float* __restrict__ in, unsigned short* __restrict__ out, size_t n)
{
    size_t i = ((size_t)blockIdx.x * 256 + threadIdx.x) * 4;
    if (i >= n) return;
    float4 v = *(const float4*)(in + i);
    unsigned long long pk = (unsigned long long)f2bf(v.x)
        | ((unsigned long long)f2bf(v.y) << 16)
        | ((unsigned long long)f2bf(v.z) << 32)
        | ((unsigned long long)f2bf(v.w) << 48);
    *(unsigned long long*)(out + i) = pk;
}

// ---------------- W [K,N] fp32 -> Wt [N,K] bf16 ----------------
__global__ __launch_bounds__(256) void transpose_cast(
    const float* __restrict__ W, unsigned short* __restrict__ Wt, int K, int N)
{
    __shared__ float t[32][33];
    int n0 = blockIdx.x * 32, k0 = blockIdx.y * 32;
    int tx = threadIdx.x & 31, ty = threadIdx.x >> 5;  // ty 0..7
#pragma unroll
    for (int i = 0; i < 4; i++)
        t[ty * 4 + i][tx] = W[(size_t)(k0 + ty * 4 + i) * N + n0 + tx];
    __syncthreads();
#pragma unroll
    for (int i = 0; i < 4; i++)
        Wt[(size_t)(n0 + ty * 4 + i) * K + k0 + tx] = f2bf(t[tx][ty * 4 + i]);
}

// ---------------- NT GEMM: C[m,n] = sum_k A[m,k]*Bt[n,k] (+bias) ----------------
// MODE 0: fp32 out; 1: bf16 out; 2: relu -> bf16 out
template<int MODE>
__global__ __launch_bounds__(256, 2) void gemm_bt(
    const unsigned short* __restrict__ A, const unsigned short* __restrict__ Bt,
    const float* __restrict__ bias, void* __restrict__ Cout,
    int M, int N, int K)
{
    (void)M;
    __shared__ unsigned short As[128 * 40];
    __shared__ unsigned short Bs[128 * 40];
    const int tid  = threadIdx.x;
    const int wid  = tid >> 6, lane = tid & 63;
    const int l16  = lane & 15, lhi = lane >> 4;
    const int wr   = wid >> 1, wc = wid & 1;
    const int bm   = blockIdx.y, bn = blockIdx.x;
    const size_t arow0 = (size_t)bm * 128;
    const size_t brow0 = (size_t)bn * 128;
    const int srow = tid >> 2, scol = (tid & 3) * 8;

    f32x4 acc[4][4];
#pragma unroll
    for (int i = 0; i < 4; i++)
#pragma unroll
        for (int j = 0; j < 4; j++) acc[i][j] = (f32x4){0.f, 0.f, 0.f, 0.f};

    for (int k0 = 0; k0 < K; k0 += 32) {
        __syncthreads();
        u16x8 a0 = *(const u16x8*)(A + (arow0 + srow) * K + k0 + scol);
        u16x8 a1 = *(const u16x8*)(A + (arow0 + 64 + srow) * K + k0 + scol);
        u16x8 b0 = *(const u16x8*)(Bt + (brow0 + srow) * K + k0 + scol);
        u16x8 b1 = *(const u16x8*)(Bt + (brow0 + 64 + srow) * K + k0 + scol);
        *(u16x8*)(As + srow * 40 + scol)        = a0;
        *(u16x8*)(As + (64 + srow) * 40 + scol) = a1;
        *(u16x8*)(Bs + srow * 40 + scol)        = b0;
        *(u16x8*)(Bs + (64 + srow) * 40 + scol) = b1;
        __syncthreads();
        u16x8 af[4], bfr[4];
#pragma unroll
        for (int i = 0; i < 4; i++)
            af[i] = *(const u16x8*)(As + (wr * 64 + i * 16 + l16) * 40 + lhi * 8);
#pragma unroll
        for (int i = 0; i < 4; i++)
            bfr[i] = *(const u16x8*)(Bs + (wc * 64 + i * 16 + l16) * 40 + lhi * 8);
#pragma unroll
        for (int mi = 0; mi < 4; mi++)
#pragma unroll
            for (int ni = 0; ni < 4; ni++)
                acc[mi][ni] = mfma32(af[mi], bfr[ni], acc[mi][ni]);
    }

#pragma unroll
    for (int mi = 0; mi < 4; mi++)
#pragma unroll
        for (int ni = 0; ni < 4; ni++) {
            int row = bm * 128 + wr * 64 + mi * 16 + lhi * 4;
            int col = bn * 128 + wc * 64 + ni * 16 + l16;
            float bv = bias ? bias[col] : 0.f;
#pragma unroll
            for (int j = 0; j < 4; j++) {
                float v = acc[mi][ni][j] + bv;
                size_t idx = (size_t)(row + j) * N + col;
                if constexpr (MODE == 0) {
                    ((float*)Cout)[idx] = v;
                } else if constexpr (MODE == 1) {
                    ((unsigned short*)Cout)[idx] = f2bf(v);
                } else {
                    ((unsigned short*)Cout)[idx] = f2bf(v > 0.f ? v : 0.f);
                }
            }
        }
}

// ---------------- flash attention (causal), 64 q-rows/block ----------------
__global__ __launch_bounds__(256, 2) void attn_fwd(
    const unsigned short* __restrict__ qb, const unsigned short* __restrict__ kb,
    const unsigned short* __restrict__ vb, unsigned short* __restrict__ ctxb)
{
    __shared__ unsigned short Ks[64 * 72];
    __shared__ unsigned short Vs[64 * 72];   // transposed: Vs[d][kv]
    __shared__ unsigned short Ps[4 * 16 * 72];
    const int tid = threadIdx.x;
    const int wid = tid >> 6, lane = tid & 63;
    const int l16 = lane & 15, lhi = lane >> 4;
    const int bh  = blockIdx.y, b = bh >> 4, h = bh & 15;
    const int q0  = blockIdx.x * 64;
    const size_t rowbase = (size_t)b * SEQ;

    const int qrow = q0 + wid * 16 + l16;
    const unsigned short* qp = qb + (rowbase + qrow) * D_MODEL + h * HDIM + lhi * 8;
    u16x8 qf0 = *(const u16x8*)qp;
    u16x8 qf1 = *(const u16x8*)(qp + 32);

    f32x4 oa[4];
    float mj[4], lj[4];
#pragma unroll
    for (int i = 0; i < 4; i++) {
        oa[i] = (f32x4){0.f, 0.f, 0.f, 0.f};
        mj[i] = -1e30f; lj[i] = 0.f;
    }

    const int ntiles = blockIdx.x + 1;
    for (int kt = 0; kt < ntiles; ++kt) {
        const int kv0 = kt * 64;
        __syncthreads();
#pragma unroll
        for (int it = 0; it < 2; ++it) {
            int e = it * 256 + tid;
            int r = e >> 3, d0 = (e & 7) * 8;
            size_t goff = (rowbase + kv0 + r) * D_MODEL + h * HDIM + d0;
            u16x8 kk = *(const u16x8*)(kb + goff);
            *(u16x8*)(&Ks[r * 72 + d0]) = kk;
            u16x8 vv = *(const u16x8*)(vb + goff);
#pragma unroll
            for (int j = 0; j < 8; j++) Vs[(d0 + j) * 72 + r] = vv[j];
        }
        __syncthreads();

        f32x4 sa[4];
#pragma unroll
        for (int ni = 0; ni < 4; ni++) {
            f32x4 z = (f32x4){0.f, 0.f, 0.f, 0.f};
            u16x8 k0f = *(const u16x8*)(&Ks[(ni * 16 + l16) * 72 + lhi * 8]);
            u16x8 k1f = *(const u16x8*)(&Ks[(ni * 16 + l16) * 72 + 32 + lhi * 8]);
            z = mfma32(qf0, k0f, z);
            z = mfma32(qf1, k1f, z);
            sa[ni] = z;
        }
        float tm[4] = {-1e30f, -1e30f, -1e30f, -1e30f};
#pragma unroll
        for (int ni = 0; ni < 4; ni++)
#pragma unroll
            for (int j = 0; j < 4; j++) {
                float v = sa[ni][j] * 0.125f;
                int row = q0 + wid * 16 + lhi * 4 + j;
                int col = kv0 + ni * 16 + l16;
                if (col > row) v = -1e30f;
                sa[ni][j] = v;
                tm[j] = fmaxf(tm[j], v);
            }
#pragma unroll
        for (int j = 0; j < 4; j++) {
#pragma unroll
            for (int off = 1; off < 16; off <<= 1)
                tm[j] = fmaxf(tm[j], __shfl_xor(tm[j], off));
        }
        float al[4], rs[4] = {0.f, 0.f, 0.f, 0.f};
#pragma unroll
        for (int j = 0; j < 4; j++) {
            float mn = fmaxf(mj[j], tm[j]);
            al[j] = __expf(mj[j] - mn);
            mj[j] = mn;
        }
#pragma unroll
        for (int ni = 0; ni < 4; ni++)
#pragma unroll
            for (int j = 0; j < 4; j++) {
                float p = __expf(sa[ni][j] - mj[j]);
                rs[j] += p;
                Ps[wid * 1152 + (lhi * 4 + j) * 72 + ni * 16 + l16] = f2bf(p);
            }
#pragma unroll
        for (int j = 0; j < 4; j++) {
#pragma unroll
            for (int off = 1; off < 16; off <<= 1)
                rs[j] += __shfl_xor(rs[j], off);
            lj[j] = lj[j] * al[j] + rs[j];
        }
#pragma unroll
        for (int di = 0; di < 4; di++)
#pragma unroll
            for (int j = 0; j < 4; j++) oa[di][j] *= al[j];
        // PV (per-wave Ps region; within-wave ds ordering suffices)
#pragma unroll
        for (int di = 0; di < 4; di++) {
#pragma unroll
            for (int kc = 0; kc < 2; kc++) {
                u16x8 pf = *(const u16x8*)(&Ps[wid * 1152 + l16 * 72 + kc * 32 + lhi * 8]);
                u16x8 vf = *(const u16x8*)(&Vs[(di * 16 + l16) * 72 + kc * 32 + lhi * 8]);
                oa[di] = mfma32(pf, vf, oa[di]);
            }
        }
    }
#pragma unroll
    for (int di = 0; di < 4; di++)
#pragma unroll
        for (int j = 0; j < 4; j++) {
            int row = q0 + wid * 16 + lhi * 4 + j;
            ctxb[(rowbase + row) * D_MODEL + h * HDIM + di * 16 + l16] =
                f2bf(oa[di][j] / lj[j]);
        }
}

// ---------------- fused residual + LayerNorm (in-place on x, also bf16 out) ----------------
__global__ __launch_bounds__(256) void ln_fused(
    float* __restrict__ x, const float* __restrict__ tmp,
    const float* __restrict__ sc, const float* __restrict__ bi,
    unsigned short* __restrict__ xb)
{
    const int row = blockIdx.x;
    const int t = threadIdx.x;
    const size_t base = (size_t)row * D_MODEL + t * 4;
    float4 xv = *(const float4*)(x + base);
    float4 tv = *(const float4*)(tmp + base);
    float v0 = xv.x + tv.x, v1 = xv.y + tv.y, v2 = xv.z + tv.z, v3 = xv.w + tv.w;
    float sum = v0 + v1 + v2 + v3;
    float sq  = v0 * v0 + v1 * v1 + v2 * v2 + v3 * v3;
#pragma unroll
    for (int off = 1; off < 64; off <<= 1) {
        sum += __shfl_xor(sum, off);
        sq  += __shfl_xor(sq, off);
    }
    __shared__ float red[8];
    int wid = t >> 6, lane = t & 63;
    if (lane == 0) { red[wid] = sum; red[4 + wid] = sq; }
    __syncthreads();
    sum = red[0] + red[1] + red[2] + red[3];
    sq  = red[4] + red[5] + red[6] + red[7];
    float mu   = sum * (1.f / D_MODEL);
    float var  = sq * (1.f / D_MODEL) - mu * mu;
    float rstd = rsqrtf(var + LN_EPS);
    int c = t * 4;
    float4 sv = *(const float4*)(sc + c);
    float4 bv = *(const float4*)(bi + c);
    float y0 = sv.x * (v0 - mu) * rstd + bv.x;
    float y1 = sv.y * (v1 - mu) * rstd + bv.y;
    float y2 = sv.z * (v2 - mu) * rstd + bv.z;
    float y3 = sv.w * (v3 - mu) * rstd + bv.w;
    *(float4*)(x + base) = make_float4(y0, y1, y2, y3);
    unsigned long long pk = (unsigned long long)f2bf(y0)
        | ((unsigned long long)f2bf(y1) << 16)
        | ((unsigned long long)f2bf(y2) << 32)
        | ((unsigned long long)f2bf(y3) << 48);
    *(unsigned long long*)(xb + base) = pk;
}

// ---------------- launcher ----------------
extern "C" void kernel_launch(void* const* d_in, const int* in_sizes, int n_in,
                              void* d_out, int out_size, void* d_ws, size_t ws_size,
                              hipStream_t stream)
{
    (void)in_sizes; (void)n_in; (void)out_size;
    const int*   tokens = (const int*)d_in[0];
    const float* emb  = (const float*)d_in[2];
    const float* pose = (const float*)d_in[3];
    const float* Wq = (const float*)d_in[4];
    const float* bq = (const float*)d_in[5];
    const float* Wk = (const float*)d_in[6];
    const float* bk = (const float*)d_in[7];
    const float* Wv = (const float*)d_in[8];
    const float* bv = (const float*)d_in[9];
    const float* Wo = (const float*)d_in[10];
    const float* bo = (const float*)d_in[11];
    const float* n1s = (const float*)d_in[12];
    const float* n1b = (const float*)d_in[13];
    const float* W1 = (const float*)d_in[14];
    const float* b1 = (const float*)d_in[15];
    const float* W2 = (const float*)d_in[16];
    const float* b2 = (const float*)d_in[17];
    const float* n2s = (const float*)d_in[18];
    const float* n2b = (const float*)d_in[19];

    char* w = (char*)d_ws;
    size_t off = 0;
    auto carve = [&](size_t bytes) -> void* {
        void* p = w + off;
        off = (off + bytes + 255) & ~(size_t)255;
        return p;
    };
    float* x   = (float*)carve((size_t)ROWS * D_MODEL * 4);
    float* tmp = (float*)carve((size_t)ROWS * D_MODEL * 4);
    unsigned short* xb   = (unsigned short*)carve((size_t)ROWS * D_MODEL * 2);
    unsigned short* qbuf = (unsigned short*)carve((size_t)ROWS * D_MODEL * 2);
    unsigned short* kbuf = (unsigned short*)carve((size_t)ROWS * D_MODEL * 2);
    unsigned short* vbuf = (unsigned short*)carve((size_t)ROWS * D_MODEL * 2);
    unsigned short* cbuf = (unsigned short*)carve((size_t)ROWS * D_MODEL * 2);
    unsigned short* hbuf = (unsigned short*)carve((size_t)ROWS * FF_DIM * 2);
    unsigned short* wt   = (unsigned short*)carve((size_t)D_MODEL * FF_DIM * 2);
    // tied-head emb (bf16) aliases qbuf..hbuf (dead by then): needs 65.5MB < 67.1MB
    unsigned short* embb = qbuf;
    if (off > ws_size) return;  // ws too small: fail visibly, no corruption

    embed_k<<<ROWS, 256, 0, stream>>>(tokens, emb, pose, x, xb);

    for (int l = 0; l < NLAYER; l++) {
        const float* Wq_l = Wq + (size_t)l * D_MODEL * D_MODEL;
        const float* Wk_l = Wk + (size_t)l * D_MODEL * D_MODEL;
        const float* Wv_l = Wv + (size_t)l * D_MODEL * D_MODEL;
        const float* Wo_l = Wo + (size_t)l * D_MODEL * D_MODEL;
        const float* W1_l = W1 + (size_t)l * D_MODEL * FF_DIM;
        const float* W2_l = W2 + (size_t)l * FF_DIM * D_MODEL;

        transpose_cast<<<dim3(32, 32), 256, 0, stream>>>(Wq_l, wt, D_MODEL, D_MODEL);
        gemm_bt<1><<<dim3(8, 32), 256, 0, stream>>>(xb, wt, bq + l * D_MODEL, qbuf, ROWS, D_MODEL, D_MODEL);
        transpose_cast<<<dim3(32, 32), 256, 0, stream>>>(Wk_l, wt, D_MODEL, D_MODEL);
        gemm_bt<1><<<dim3(8, 32), 256, 0, stream>>>(xb, wt, bk + l * D_MODEL, kbuf, ROWS, D_MODEL, D_MODEL);
        transpose_cast<<<dim3(32, 32), 256, 0, stream>>>(Wv_l, wt, D_MODEL, D_MODEL);
        gemm_bt<1><<<dim3(8, 32), 256, 0, stream>>>(xb, wt, bv + l * D_MODEL, vbuf, ROWS, D_MODEL, D_MODEL);

        attn_fwd<<<dim3(SEQ / 64, BATCH * NHEAD), 256, 0, stream>>>(qbuf, kbuf, vbuf, cbuf);

        transpose_cast<<<dim3(32, 32), 256, 0, stream>>>(Wo_l, wt, D_MODEL, D_MODEL);
        gemm_bt<0><<<dim3(8, 32), 256, 0, stream>>>(cbuf, wt, bo + l * D_MODEL, tmp, ROWS, D_MODEL, D_MODEL);
        ln_fused<<<ROWS, 256, 0, stream>>>(x, tmp, n1s + l * D_MODEL, n1b + l * D_MODEL, xb);

        transpose_cast<<<dim3(FF_DIM / 32, D_MODEL / 32), 256, 0, stream>>>(W1_l, wt, D_MODEL, FF_DIM);
        gemm_bt<2><<<dim3(FF_DIM / 128, 32), 256, 0, stream>>>(xb, wt, b1 + l * FF_DIM, hbuf, ROWS, FF_DIM, D_MODEL);
        transpose_cast<<<dim3(D_MODEL / 32, FF_DIM / 32), 256, 0, stream>>>(W2_l, wt, FF_DIM, D_MODEL);
        gemm_bt<0><<<dim3(8, 32), 256, 0, stream>>>(hbuf, wt, b2 + l * D_MODEL, tmp, ROWS, D_MODEL, FF_DIM);
        ln_fused<<<ROWS, 256, 0, stream>>>(x, tmp, n2s + l * D_MODEL, n2b + l * D_MODEL, xb);
    }

    cast_bf<<<(VOCAB * D_MODEL) / 1024, 256, 0, stream>>>(emb, embb, (size_t)VOCAB * D_MODEL);
    gemm_bt<0><<<dim3(VOCAB / 128, ROWS / 128), 256, 0, stream>>>(xb, embb, nullptr, d_out, ROWS, VOCAB, D_MODEL);
}

// Round 2
// 2962.605 us; speedup vs baseline: 1.1604x; 1.1604x over previous
//
#include <hip/hip_runtime.h>

#define D_MODEL 1024
#define SEQ     1024
#define BATCH   4
#define NHEAD   16
#define HDIM    64
#define FF_DIM  4096
#define NLAYER  8
#define VOCAB   32000
#define ROWS    (BATCH*SEQ)
#define QKV_N   3072
#define LN_EPS  1e-5f

typedef __attribute__((ext_vector_type(4))) float   f32x4;
typedef __attribute__((ext_vector_type(8))) unsigned short u16x8;
typedef __attribute__((ext_vector_type(8))) __bf16  bf16x8;

typedef const unsigned int __attribute__((address_space(1)))* gas_t;
typedef unsigned int __attribute__((address_space(3)))* las_t;

__device__ __forceinline__ void gld16(const void* g, void* l) {
    __builtin_amdgcn_global_load_lds((gas_t)g, (las_t)l, 16, 0, 0);
}

__device__ __forceinline__ unsigned short f2bf(float f) {
    unsigned int u = __builtin_bit_cast(unsigned int, f);
    u += 0x7FFFu + ((u >> 16) & 1u);   // RNE
    return (unsigned short)(u >> 16);
}

__device__ __forceinline__ f32x4 mfma32(u16x8 a, u16x8 b, f32x4 c) {
    return __builtin_amdgcn_mfma_f32_16x16x32_bf16(
        __builtin_bit_cast(bf16x8, a), __builtin_bit_cast(bf16x8, b), c, 0, 0, 0);
}

// ---------------- embed: x = emb[tok] + pos ----------------
__global__ __launch_bounds__(256) void embed_k(
    const int* __restrict__ tok, const float* __restrict__ emb,
    const float* __restrict__ pos, float* __restrict__ x,
    unsigned short* __restrict__ xb)
{
    int bs = blockIdx.x;
    int s  = bs & (SEQ - 1);
    int tk = tok[bs];
    int c  = threadIdx.x * 4;
    float4 e = *(const float4*)(emb + (size_t)tk * D_MODEL + c);
    float4 p = *(const float4*)(pos + (size_t)s * D_MODEL + c);
    float y0 = e.x + p.x, y1 = e.y + p.y, y2 = e.z + p.z, y3 = e.w + p.w;
    size_t base = (size_t)bs * D_MODEL + c;
    *(float4*)(x + base) = make_float4(y0, y1, y2, y3);
    unsigned long long pk = (unsigned long long)f2bf(y0)
        | ((unsigned long long)f2bf(y1) << 16)
        | ((unsigned long long)f2bf(y2) << 32)
        | ((unsigned long long)f2bf(y3) << 48);
    *(unsigned long long*)(xb + base) = pk;
}

// ---------------- cast fp32 -> bf16 ----------------
__global__ __launch_bounds__(256) void cast_bf(
    const float* __restrict__ in, unsigned short* __restrict__ out, size_t n)
{
    size_t i = ((size_t)blockIdx.x * 256 + threadIdx.x) * 4;
    if (i >= n) return;
    float4 v = *(const float4*)(in + i);
    unsigned long long pk = (unsigned long long)f2bf(v.x)
        | ((unsigned long long)f2bf(v.y) << 16)
        | ((unsigned long long)f2bf(v.z) << 32)
        | ((unsigned long long)f2bf(v.w) << 48);
    *(unsigned long long*)(out + i) = pk;
}

// ---------------- concat qkv biases: bqkv[l][0:1024]=bq[l], [1024:2048]=bk[l], [2048:3072]=bv[l]
__global__ __launch_bounds__(256) void bias3_k(
    const float* __restrict__ bq, const float* __restrict__ bk,
    const float* __restrict__ bv, float* __restrict__ out)
{
    int l = blockIdx.x / 3, which = blockIdx.x % 3;
    const float* src = which == 0 ? bq : (which == 1 ? bk : bv);
    int i = threadIdx.x * 4;
    float4 v = *(const float4*)(src + (size_t)l * D_MODEL + i);
    *(float4*)(out + (size_t)l * QKV_N + which * D_MODEL + i) = v;
}

// ---------------- W [K,N] fp32 -> Wt [N,K] bf16, 64x64 tiles ----------------
__global__ __launch_bounds__(256) void transpose_cast(
    const float* __restrict__ W, unsigned short* __restrict__ Wt, int K, int N)
{
    __shared__ float t[64][65];
    int n0 = blockIdx.x * 64, k0 = blockIdx.y * 64;
    int rr = threadIdx.x >> 4;          // 0..15
    int cc = (threadIdx.x & 15) * 4;    // 0..60
#pragma unroll
    for (int it = 0; it < 4; it++) {
        int r = it * 16 + rr;
        float4 v = *(const float4*)(W + (size_t)(k0 + r) * N + n0 + cc);
        t[r][cc] = v.x; t[r][cc + 1] = v.y; t[r][cc + 2] = v.z; t[r][cc + 3] = v.w;
    }
    __syncthreads();
#pragma unroll
    for (int it = 0; it < 4; it++) {
        int n = it * 16 + rr;
        unsigned long long pk = (unsigned long long)f2bf(t[cc][n])
            | ((unsigned long long)f2bf(t[cc + 1][n]) << 16)
            | ((unsigned long long)f2bf(t[cc + 2][n]) << 32)
            | ((unsigned long long)f2bf(t[cc + 3][n]) << 48);
        *(unsigned long long*)(Wt + (size_t)(n0 + n) * K + k0 + cc) = pk;
    }
}

// ---------------- NT GEMM, m97 structure: global_load_lds w16, linear LDS ----------------
// C[m,n] = sum_k A[m,k]*Bt[n,k] (+bias). M fixed = 4096 (32 bm tiles).
// Flat 1-D grid, column-major decode (bm = flat%32) for B-panel L2 reuse.
// MODE 0: fp32 out; 1: bf16 out; 2: relu -> bf16 out
template<int MODE, int SWZ>
__global__ __launch_bounds__(256, 3) void gemm_bt(
    const unsigned short* __restrict__ A, const unsigned short* __restrict__ Bt,
    const float* __restrict__ bias, void* __restrict__ Cout, int N, int K)
{
    __shared__ unsigned short As[128 * 32];
    __shared__ unsigned short Bs[128 * 32];
    int flat = blockIdx.x;
    if constexpr (SWZ) {
        int cpx = gridDim.x >> 3;           // gridDim.x % 8 == 0 guaranteed
        flat = (flat & 7) * cpx + (flat >> 3);
    }
    const int bm = flat & 31, bn = flat >> 5;
    const int tid  = threadIdx.x;
    const int wid  = tid >> 6, lane = tid & 63;
    const int l16  = lane & 15, lhi = lane >> 4;
    const int wr   = wid >> 1, wc = wid & 1;

    // staging: wave w loads rows [w*32, w*32+32) of each 128-row tile, 16B/lane
    const int srow = wid * 32 + (lane >> 2);
    const int scol = (lane & 3) * 8;
    const unsigned short* gA0 = A  + ((size_t)bm * 128 + srow) * K + scol;
    const unsigned short* gB0 = Bt + ((size_t)bn * 128 + srow) * K + scol;
    unsigned short* lA = As + wid * 32 * 32;   // wave-uniform; HW adds lane*16B
    unsigned short* lB = Bs + wid * 32 * 32;

    f32x4 acc[4][4];
#pragma unroll
    for (int i = 0; i < 4; i++)
#pragma unroll
        for (int j = 0; j < 4; j++) acc[i][j] = (f32x4){0.f, 0.f, 0.f, 0.f};

    for (int k0 = 0; k0 < K; k0 += 32) {
        __syncthreads();                       // prior ds_reads done before overwrite
        gld16(gA0 + k0,            lA);
        gld16(gA0 + k0 + 16 * (size_t)K, lA + 16 * 32);
        gld16(gB0 + k0,            lB);
        gld16(gB0 + k0 + 16 * (size_t)K, lB + 16 * 32);
        __syncthreads();                       // compiler drains vmcnt before barrier
        u16x8 af[4], bfr[4];
#pragma unroll
        for (int i = 0; i < 4; i++)
            af[i] = *(const u16x8*)(As + (wr * 64 + i * 16 + l16) * 32 + lhi * 8);
#pragma unroll
        for (int i = 0; i < 4; i++)
            bfr[i] = *(const u16x8*)(Bs + (wc * 64 + i * 16 + l16) * 32 + lhi * 8);
#pragma unroll
        for (int mi = 0; mi < 4; mi++)
#pragma unroll
            for (int ni = 0; ni < 4; ni++)
                acc[mi][ni] = mfma32(af[mi], bfr[ni], acc[mi][ni]);
    }

#pragma unroll
    for (int mi = 0; mi < 4; mi++)
#pragma unroll
        for (int ni = 0; ni < 4; ni++) {
            int row = bm * 128 + wr * 64 + mi * 16 + lhi * 4;
            int col = bn * 128 + wc * 64 + ni * 16 + l16;
            float bv = bias ? bias[col] : 0.f;
#pragma unroll
            for (int j = 0; j < 4; j++) {
                float v = acc[mi][ni][j] + bv;
                size_t idx = (size_t)(row + j) * N + col;
                if constexpr (MODE == 0) {
                    ((float*)Cout)[idx] = v;
                } else if constexpr (MODE == 1) {
                    ((unsigned short*)Cout)[idx] = f2bf(v);
                } else {
                    ((unsigned short*)Cout)[idx] = f2bf(v > 0.f ? v : 0.f);
                }
            }
        }
}

// ---------------- flash attention (causal), 64 q-rows/block, fused qkv input ----------------
__global__ __launch_bounds__(256, 2) void attn_fwd(
    const unsigned short* __restrict__ qkv, unsigned short* __restrict__ ctxb)
{
    __shared__ unsigned short Ks[64 * 72];
    __shared__ unsigned short Vs[64 * 72];   // transposed: Vs[d][kv]
    __shared__ unsigned short Ps[4 * 16 * 72];
    const int tid = threadIdx.x;
    const int wid = tid >> 6, lane = tid & 63;
    const int l16 = lane & 15, lhi = lane >> 4;
    const int bh  = blockIdx.y, b = bh >> 4, h = bh & 15;
    const int q0  = blockIdx.x * 64;
    const size_t rowbase = (size_t)b * SEQ;

    const int qrow = q0 + wid * 16 + l16;
    const unsigned short* qp = qkv + (rowbase + qrow) * QKV_N + h * HDIM + lhi * 8;
    u16x8 qf0 = *(const u16x8*)qp;
    u16x8 qf1 = *(const u16x8*)(qp + 32);

    f32x4 oa[4];
    float mj[4], lj[4];
#pragma unroll
    for (int i = 0; i < 4; i++) {
        oa[i] = (f32x4){0.f, 0.f, 0.f, 0.f};
        mj[i] = -1e30f; lj[i] = 0.f;
    }

    const int ntiles = blockIdx.x + 1;
    for (int kt = 0; kt < ntiles; ++kt) {
        const int kv0 = kt * 64;
        __syncthreads();
#pragma unroll
        for (int it = 0; it < 2; ++it) {
            int e = it * 256 + tid;
            int r = e >> 3, d0 = (e & 7) * 8;
            size_t goff = (rowbase + kv0 + r) * QKV_N + D_MODEL + h * HDIM + d0;
            u16x8 kk = *(const u16x8*)(qkv + goff);
            *(u16x8*)(&Ks[r * 72 + d0]) = kk;
            u16x8 vv = *(const u16x8*)(qkv + goff + D_MODEL);
#pragma unroll
            for (int j = 0; j < 8; j++) Vs[(d0 + j) * 72 + r] = vv[j];
        }
        __syncthreads();

        f32x4 sa[4];
#pragma unroll
        for (int ni = 0; ni < 4; ni++) {
            f32x4 z = (f32x4){0.f, 0.f, 0.f, 0.f};
            u16x8 k0f = *(const u16x8*)(&Ks[(ni * 16 + l16) * 72 + lhi * 8]);
            u16x8 k1f = *(const u16x8*)(&Ks[(ni * 16 + l16) * 72 + 32 + lhi * 8]);
            z = mfma32(qf0, k0f, z);
            z = mfma32(qf1, k1f, z);
            sa[ni] = z;
        }
        float tm[4] = {-1e30f, -1e30f, -1e30f, -1e30f};
#pragma unroll
        for (int ni = 0; ni < 4; ni++)
#pragma unroll
            for (int j = 0; j < 4; j++) {
                float v = sa[ni][j] * 0.125f;
                int row = q0 + wid * 16 + lhi * 4 + j;
                int col = kv0 + ni * 16 + l16;
                if (col > row) v = -1e30f;
                sa[ni][j] = v;
                tm[j] = fmaxf(tm[j], v);
            }
#pragma unroll
        for (int j = 0; j < 4; j++) {
#pragma unroll
            for (int off = 1; off < 16; off <<= 1)
                tm[j] = fmaxf(tm[j], __shfl_xor(tm[j], off));
        }
        float al[4], rs[4] = {0.f, 0.f, 0.f, 0.f};
#pragma unroll
        for (int j = 0; j < 4; j++) {
            float mn = fmaxf(mj[j], tm[j]);
            al[j] = __expf(mj[j] - mn);
            mj[j] = mn;
        }
#pragma unroll
        for (int ni = 0; ni < 4; ni++)
#pragma unroll
            for (int j = 0; j < 4; j++) {
                float p = __expf(sa[ni][j] - mj[j]);
                rs[j] += p;
                Ps[wid * 1152 + (lhi * 4 + j) * 72 + ni * 16 + l16] = f2bf(p);
            }
#pragma unroll
        for (int j = 0; j < 4; j++) {
#pragma unroll
            for (int off = 1; off < 16; off <<= 1)
                rs[j] += __shfl_xor(rs[j], off);
            lj[j] = lj[j] * al[j] + rs[j];
        }
#pragma unroll
        for (int di = 0; di < 4; di++)
#pragma unroll
            for (int j = 0; j < 4; j++) oa[di][j] *= al[j];
#pragma unroll
        for (int di = 0; di < 4; di++) {
#pragma unroll
            for (int kc = 0; kc < 2; kc++) {
                u16x8 pf = *(const u16x8*)(&Ps[wid * 1152 + l16 * 72 + kc * 32 + lhi * 8]);
                u16x8 vf = *(const u16x8*)(&Vs[(di * 16 + l16) * 72 + kc * 32 + lhi * 8]);
                oa[di] = mfma32(pf, vf, oa[di]);
            }
        }
    }
#pragma unroll
    for (int di = 0; di < 4; di++)
#pragma unroll
        for (int j = 0; j < 4; j++) {
            int row = q0 + wid * 16 + lhi * 4 + j;
            ctxb[(rowbase + row) * D_MODEL + h * HDIM + di * 16 + l16] =
                f2bf(oa[di][j] / lj[j]);
        }
}

// ---------------- fused residual + LayerNorm ----------------
__global__ __launch_bounds__(256) void ln_fused(
    float* __restrict__ x, const float* __restrict__ tmp,
    const float* __restrict__ sc, const float* __restrict__ bi,
    unsigned short* __restrict__ xb)
{
    const int row = blockIdx.x;
    const int t = threadIdx.x;
    const size_t base = (size_t)row * D_MODEL + t * 4;
    float4 xv = *(const float4*)(x + base);
    float4 tv = *(const float4*)(tmp + base);
    float v0 = xv.x + tv.x, v1 = xv.y + tv.y, v2 = xv.z + tv.z, v3 = xv.w + tv.w;
    float sum = v0 + v1 + v2 + v3;
    float sq  = v0 * v0 + v1 * v1 + v2 * v2 + v3 * v3;
#pragma unroll
    for (int off = 1; off < 64; off <<= 1) {
        sum += __shfl_xor(sum, off);
        sq  += __shfl_xor(sq, off);
    }
    __shared__ float red[8];
    int wid = t >> 6, lane = t & 63;
    if (lane == 0) { red[wid] = sum; red[4 + wid] = sq; }
    __syncthreads();
    sum = red[0] + red[1] + red[2] + red[3];
    sq  = red[4] + red[5] + red[6] + red[7];
    float mu   = sum * (1.f / D_MODEL);
    float var  = sq * (1.f / D_MODEL) - mu * mu;
    float rstd = rsqrtf(var + LN_EPS);
    int c = t * 4;
    float4 sv = *(const float4*)(sc + c);
    float4 bv = *(const float4*)(bi + c);
    float y0 = sv.x * (v0 - mu) * rstd + bv.x;
    float y1 = sv.y * (v1 - mu) * rstd + bv.y;
    float y2 = sv.z * (v2 - mu) * rstd + bv.z;
    float y3 = sv.w * (v3 - mu) * rstd + bv.w;
    *(float4*)(x + base) = make_float4(y0, y1, y2, y3);
    unsigned long long pk = (unsigned long long)f2bf(y0)
        | ((unsigned long long)f2bf(y1) << 16)
        | ((unsigned long long)f2bf(y2) << 32)
        | ((unsigned long long)f2bf(y3) << 48);
    *(unsigned long long*)(xb + base) = pk;
}

// ---------------- launcher ----------------
extern "C" void kernel_launch(void* const* d_in, const int* in_sizes, int n_in,
                              void* d_out, int out_size, void* d_ws, size_t ws_size,
                              hipStream_t stream)
{
    (void)in_sizes; (void)n_in; (void)out_size;
    const int*   tokens = (const int*)d_in[0];
    const float* emb  = (const float*)d_in[2];
    const float* pose = (const float*)d_in[3];
    const float* Wq = (const float*)d_in[4];
    const float* bq = (const float*)d_in[5];
    const float* Wk = (const float*)d_in[6];
    const float* bk = (const float*)d_in[7];
    const float* Wv = (const float*)d_in[8];
    const float* bv = (const float*)d_in[9];
    const float* Wo = (const float*)d_in[10];
    const float* bo = (const float*)d_in[11];
    const float* n1s = (const float*)d_in[12];
    const float* n1b = (const float*)d_in[13];
    const float* W1 = (const float*)d_in[14];
    const float* b1 = (const float*)d_in[15];
    const float* W2 = (const float*)d_in[16];
    const float* b2 = (const float*)d_in[17];
    const float* n2s = (const float*)d_in[18];
    const float* n2b = (const float*)d_in[19];

    char* w = (char*)d_ws;
    size_t off = 0;
    auto carve = [&](size_t bytes) -> void* {
        void* p = w + off;
        off = (off + bytes + 255) & ~(size_t)255;
        return p;
    };
    float* x   = (float*)carve((size_t)ROWS * D_MODEL * 4);
    float* tmp = (float*)carve((size_t)ROWS * D_MODEL * 4);
    unsigned short* xb    = (unsigned short*)carve((size_t)ROWS * D_MODEL * 2);
    unsigned short* qkvb  = (unsigned short*)carve((size_t)ROWS * QKV_N * 2);
    unsigned short* cbuf  = (unsigned short*)carve((size_t)ROWS * D_MODEL * 2);
    unsigned short* hbuf  = (unsigned short*)carve((size_t)ROWS * FF_DIM * 2);
    unsigned short* wt    = (unsigned short*)carve((size_t)D_MODEL * FF_DIM * 2);
    float* bqkv = (float*)carve((size_t)NLAYER * QKV_N * 4);
    // tied-head emb (bf16) aliases qkvb+cbuf+hbuf (dead by then): 65.5MB < 67.2MB
    unsigned short* embb = qkvb;
    if (off > ws_size) return;  // ws too small: fail visibly, no corruption

    bias3_k<<<NLAYER * 3, 256, 0, stream>>>(bq, bk, bv, bqkv);
    embed_k<<<ROWS, 256, 0, stream>>>(tokens, emb, pose, x, xb);

    for (int l = 0; l < NLAYER; l++) {
        const float* Wq_l = Wq + (size_t)l * D_MODEL * D_MODEL;
        const float* Wk_l = Wk + (size_t)l * D_MODEL * D_MODEL;
        const float* Wv_l = Wv + (size_t)l * D_MODEL * D_MODEL;
        const float* Wo_l = Wo + (size_t)l * D_MODEL * D_MODEL;
        const float* W1_l = W1 + (size_t)l * D_MODEL * FF_DIM;
        const float* W2_l = W2 + (size_t)l * FF_DIM * D_MODEL;

        // fused QKV: wt rows [0,1024)=Wq^T, [1024,2048)=Wk^T, [2048,3072)=Wv^T
        transpose_cast<<<dim3(16, 16), 256, 0, stream>>>(Wq_l, wt, D_MODEL, D_MODEL);
        transpose_cast<<<dim3(16, 16), 256, 0, stream>>>(Wk_l, wt + 1024 * 1024, D_MODEL, D_MODEL);
        transpose_cast<<<dim3(16, 16), 256, 0, stream>>>(Wv_l, wt + 2 * 1024 * 1024, D_MODEL, D_MODEL);
        gemm_bt<1, 0><<<(QKV_N / 128) * 32, 256, 0, stream>>>(xb, wt, bqkv + (size_t)l * QKV_N, qkvb, QKV_N, D_MODEL);

        attn_fwd<<<dim3(SEQ / 64, BATCH * NHEAD), 256, 0, stream>>>(qkvb, cbuf);

        transpose_cast<<<dim3(16, 16), 256, 0, stream>>>(Wo_l, wt, D_MODEL, D_MODEL);
        gemm_bt<0, 0><<<8 * 32, 256, 0, stream>>>(cbuf, wt, bo + (size_t)l * D_MODEL, tmp, D_MODEL, D_MODEL);
        ln_fused<<<ROWS, 256, 0, stream>>>(x, tmp, n1s + (size_t)l * D_MODEL, n1b + (size_t)l * D_MODEL, xb);

        transpose_cast<<<dim3(64, 16), 256, 0, stream>>>(W1_l, wt, D_MODEL, FF_DIM);
        gemm_bt<2, 0><<<32 * 32, 256, 0, stream>>>(xb, wt, b1 + (size_t)l * FF_DIM, hbuf, FF_DIM, D_MODEL);
        transpose_cast<<<dim3(16, 64), 256, 0, stream>>>(W2_l, wt, FF_DIM, D_MODEL);
        gemm_bt<0, 0><<<8 * 32, 256, 0, stream>>>(hbuf, wt, b2 + (size_t)l * D_MODEL, tmp, D_MODEL, FF_DIM);
        ln_fused<<<ROWS, 256, 0, stream>>>(x, tmp, n2s + (size_t)l * D_MODEL, n2b + (size_t)l * D_MODEL, xb);
    }

    cast_bf<<<(VOCAB * D_MODEL) / 1024, 256, 0, stream>>>(emb, embb, (size_t)VOCAB * D_MODEL);
    gemm_bt<0, 1><<<(VOCAB / 128) * 32, 256, 0, stream>>>(xb, embb, nullptr, d_out, VOCAB, D_MODEL);
}

// Round 3
// 2945.597 us; speedup vs baseline: 1.1671x; 1.0058x over previous
//
#include <hip/hip_runtime.h>

#define D_MODEL 1024
#define SEQ     1024
#define BATCH   4
#define NHEAD   16
#define HDIM    64
#define FF_DIM  4096
#define NLAYER  8
#define VOCAB   32000
#define ROWS    (BATCH*SEQ)
#define QKV_N   3072
#define LN_EPS  1e-5f

typedef __attribute__((ext_vector_type(4))) float   f32x4;
typedef __attribute__((ext_vector_type(8))) unsigned short u16x8;
typedef __attribute__((ext_vector_type(8))) __bf16  bf16x8;

typedef const unsigned int __attribute__((address_space(1)))* gas_t;
typedef unsigned int __attribute__((address_space(3)))* las_t;

__device__ __forceinline__ void gld16(const void* g, void* l) {
    __builtin_amdgcn_global_load_lds((gas_t)g, (las_t)l, 16, 0, 0);
}

__device__ __forceinline__ unsigned short f2bf(float f) {
    unsigned int u = __builtin_bit_cast(unsigned int, f);
    u += 0x7FFFu + ((u >> 16) & 1u);   // RNE
    return (unsigned short)(u >> 16);
}

__device__ __forceinline__ f32x4 mfma32(u16x8 a, u16x8 b, f32x4 c) {
    return __builtin_amdgcn_mfma_f32_16x16x32_bf16(
        __builtin_bit_cast(bf16x8, a), __builtin_bit_cast(bf16x8, b), c, 0, 0, 0);
}

// ---------------- embed: x = emb[tok] + pos ----------------
__global__ __launch_bounds__(256) void embed_k(
    const int* __restrict__ tok, const float* __restrict__ emb,
    const float* __restrict__ pos, float* __restrict__ x,
    unsigned short* __restrict__ xb)
{
    int bs = blockIdx.x;
    int s  = bs & (SEQ - 1);
    int tk = tok[bs];
    int c  = threadIdx.x * 4;
    float4 e = *(const float4*)(emb + (size_t)tk * D_MODEL + c);
    float4 p = *(const float4*)(pos + (size_t)s * D_MODEL + c);
    float y0 = e.x + p.x, y1 = e.y + p.y, y2 = e.z + p.z, y3 = e.w + p.w;
    size_t base = (size_t)bs * D_MODEL + c;
    *(float4*)(x + base) = make_float4(y0, y1, y2, y3);
    unsigned long long pk = (unsigned long long)f2bf(y0)
        | ((unsigned long long)f2bf(y1) << 16)
        | ((unsigned long long)f2bf(y2) << 32)
        | ((unsigned long long)f2bf(y3) << 48);
    *(unsigned long long*)(xb + base) = pk;
}

// ---------------- cast fp32 -> bf16 ----------------
__global__ __launch_bounds__(256) void cast_bf(
    const float* __restrict__ in, unsigned short* __restrict__ out, size_t n)
{
    size_t i = ((size_t)blockIdx.x * 256 + threadIdx.x) * 4;
    if (i >= n) return;
    float4 v = *(const float4*)(in + i);
    unsigned long long pk = (unsigned long long)f2bf(v.x)
        | ((unsigned long long)f2bf(v.y) << 16)
        | ((unsigned long long)f2bf(v.z) << 32)
        | ((unsigned long long)f2bf(v.w) << 48);
    *(unsigned long long*)(out + i) = pk;
}

// ---------------- concat qkv biases ----------------
__global__ __launch_bounds__(256) void bias3_k(
    const float* __restrict__ bq, const float* __restrict__ bk,
    const float* __restrict__ bv, float* __restrict__ out)
{
    int l = blockIdx.x / 3, which = blockIdx.x % 3;
    const float* src = which == 0 ? bq : (which == 1 ? bk : bv);
    int i = threadIdx.x * 4;
    float4 v = *(const float4*)(src + (size_t)l * D_MODEL + i);
    *(float4*)(out + (size_t)l * QKV_N + which * D_MODEL + i) = v;
}

// ---------------- W [K,N] fp32 -> Wt [N,K] bf16, 64x64 tiles ----------------
__global__ __launch_bounds__(256) void transpose_cast(
    const float* __restrict__ W, unsigned short* __restrict__ Wt, int K, int N)
{
    __shared__ float t[64][65];
    int n0 = blockIdx.x * 64, k0 = blockIdx.y * 64;
    int rr = threadIdx.x >> 4;          // 0..15
    int cc = (threadIdx.x & 15) * 4;    // 0..60
#pragma unroll
    for (int it = 0; it < 4; it++) {
        int r = it * 16 + rr;
        float4 v = *(const float4*)(W + (size_t)(k0 + r) * N + n0 + cc);
        t[r][cc] = v.x; t[r][cc + 1] = v.y; t[r][cc + 2] = v.z; t[r][cc + 3] = v.w;
    }
    __syncthreads();
#pragma unroll
    for (int it = 0; it < 4; it++) {
        int n = it * 16 + rr;
        unsigned long long pk = (unsigned long long)f2bf(t[cc][n])
            | ((unsigned long long)f2bf(t[cc + 1][n]) << 16)
            | ((unsigned long long)f2bf(t[cc + 2][n]) << 32)
            | ((unsigned long long)f2bf(t[cc + 3][n]) << 48);
        *(unsigned long long*)(Wt + (size_t)(n0 + n) * K + k0 + cc) = pk;
    }
}

// ---------------- small NT GEMM (m97 128x128), for N=1024 outputs ----------------
// MODE 0: fp32 out; 1: bf16 out; 2: relu -> bf16 out
template<int MODE>
__global__ __launch_bounds__(256, 3) void gemm_bt(
    const unsigned short* __restrict__ A, const unsigned short* __restrict__ Bt,
    const float* __restrict__ bias, void* __restrict__ Cout, int N, int K)
{
    __shared__ unsigned short As[128 * 32];
    __shared__ unsigned short Bs[128 * 32];
    int flat = blockIdx.x;
    const int bm = flat & 31, bn = flat >> 5;
    const int tid  = threadIdx.x;
    const int wid  = tid >> 6, lane = tid & 63;
    const int l16  = lane & 15, lhi = lane >> 4;
    const int wr   = wid >> 1, wc = wid & 1;

    const int srow = wid * 32 + (lane >> 2);
    const int scol = (lane & 3) * 8;
    const unsigned short* gA0 = A  + ((size_t)bm * 128 + srow) * K + scol;
    const unsigned short* gB0 = Bt + ((size_t)bn * 128 + srow) * K + scol;
    unsigned short* lA = As + wid * 32 * 32;
    unsigned short* lB = Bs + wid * 32 * 32;

    f32x4 acc[4][4];
#pragma unroll
    for (int i = 0; i < 4; i++)
#pragma unroll
        for (int j = 0; j < 4; j++) acc[i][j] = (f32x4){0.f, 0.f, 0.f, 0.f};

    for (int k0 = 0; k0 < K; k0 += 32) {
        __syncthreads();
        gld16(gA0 + k0,                  lA);
        gld16(gA0 + k0 + 16 * (size_t)K, lA + 16 * 32);
        gld16(gB0 + k0,                  lB);
        gld16(gB0 + k0 + 16 * (size_t)K, lB + 16 * 32);
        __syncthreads();
        u16x8 af[4], bfr[4];
#pragma unroll
        for (int i = 0; i < 4; i++)
            af[i] = *(const u16x8*)(As + (wr * 64 + i * 16 + l16) * 32 + lhi * 8);
#pragma unroll
        for (int i = 0; i < 4; i++)
            bfr[i] = *(const u16x8*)(Bs + (wc * 64 + i * 16 + l16) * 32 + lhi * 8);
#pragma unroll
        for (int mi = 0; mi < 4; mi++)
#pragma unroll
            for (int ni = 0; ni < 4; ni++)
                acc[mi][ni] = mfma32(af[mi], bfr[ni], acc[mi][ni]);
    }

#pragma unroll
    for (int mi = 0; mi < 4; mi++)
#pragma unroll
        for (int ni = 0; ni < 4; ni++) {
            int row = bm * 128 + wr * 64 + mi * 16 + lhi * 4;
            int col = bn * 128 + wc * 64 + ni * 16 + l16;
            float bv = bias ? bias[col] : 0.f;
#pragma unroll
            for (int j = 0; j < 4; j++) {
                float v = acc[mi][ni][j] + bv;
                size_t idx = (size_t)(row + j) * N + col;
                if constexpr (MODE == 0) {
                    ((float*)Cout)[idx] = v;
                } else if constexpr (MODE == 1) {
                    ((unsigned short*)Cout)[idx] = f2bf(v);
                } else {
                    ((unsigned short*)Cout)[idx] = f2bf(v > 0.f ? v : 0.f);
                }
            }
        }
}

// ---------------- big NT GEMM: 256x256 tile, BK=32, 8 waves, 4 LDS buffers ----------------
// Deep pipeline: compute tile t (buf t%4) while staging tile t+2 (buf (t+2)%4).
// Per-wave issue order ...,A(t+1),B(t+1),A(t+2),B(t+2) => vmcnt(4) at P2
// guarantees tile t+1 resident; barrier makes it cross-wave. Never drains to 0.
// M fixed 4096 (16 bm tiles). Grid flat, XCD-swizzled (grid%8==0), bm fastest.
template<int MODE>
__global__ __launch_bounds__(512, 2) void gemm256(
    const unsigned short* __restrict__ A, const unsigned short* __restrict__ Bt,
    const float* __restrict__ bias, void* __restrict__ Cout, int N, int K)
{
    __shared__ unsigned short lds[65536] __attribute__((aligned(128)));  // 128 KiB
    const int tid = threadIdx.x, wid = tid >> 6, lane = tid & 63;
    const int l16 = lane & 15, lhi = lane >> 4;
    const int wr = wid >> 2, wc = wid & 3;

    int flat = blockIdx.x;
    { int cpx = gridDim.x >> 3; flat = (flat & 7) * cpx + (flat >> 3); }
    const int bm = flat & 15, bn = flat >> 4;
    const int NT = K >> 5;

    const int srow   = wid * 16 + (lane >> 2);   // tid/4: 0..127
    const int schunk = lane & 3;
    const unsigned short* gA = A  + ((size_t)bm * 256 + srow) * K + schunk * 8;
    const unsigned short* gB = Bt + ((size_t)bn * 256 + srow) * K + schunk * 8;

    auto stageA = [&](int t) {
        const unsigned short* s = gA + t * 32;
        unsigned short* d = lds + (t & 3) * 16384 + wid * 512;   // wave-uniform base
        gld16(s, d);
        gld16(s + (size_t)128 * K, d + 4096);
    };
    auto stageB = [&](int t) {
        const unsigned short* s = gB + t * 32;
        unsigned short* d = lds + (t & 3) * 16384 + 8192 + wid * 512;
        gld16(s, d);
        gld16(s + (size_t)128 * K, d + 4096);
    };

    f32x4 acc[8][4];
#pragma unroll
    for (int i = 0; i < 8; i++)
#pragma unroll
        for (int j = 0; j < 4; j++) acc[i][j] = (f32x4){0.f, 0.f, 0.f, 0.f};

    // prologue: stage tiles 0,1; wait tile 0 (4 newest = tile 1 stay in flight)
    stageA(0); stageB(0); stageA(1); stageB(1);
    asm volatile("s_waitcnt vmcnt(4)" ::: "memory");
    __builtin_amdgcn_s_barrier();

    for (int t = 0; t < NT; ++t) {
        const unsigned short* Ab = lds + (t & 3) * 16384;
        const unsigned short* Bb = Ab + 8192;
        u16x8 af[4], bfr[4];
        // ---- phase 1: quadrant m0..3 x n0..3 ----
#pragma unroll
        for (int m = 0; m < 4; m++)
            af[m] = *(const u16x8*)(Ab + (wr * 128 + m * 16 + l16) * 32 + lhi * 8);
#pragma unroll
        for (int n = 0; n < 4; n++)
            bfr[n] = *(const u16x8*)(Bb + (wc * 64 + n * 16 + l16) * 32 + lhi * 8);
        if (t + 2 < NT) stageA(t + 2);
        __builtin_amdgcn_s_barrier();
        __builtin_amdgcn_sched_barrier(0);
        __builtin_amdgcn_s_setprio(1);
#pragma unroll
        for (int m = 0; m < 4; m++)
#pragma unroll
            for (int n = 0; n < 4; n++)
                acc[m][n] = mfma32(af[m], bfr[n], acc[m][n]);
        __builtin_amdgcn_s_setprio(0);
        __builtin_amdgcn_s_barrier();
        // ---- phase 2: quadrant m4..7 x n0..3 ----
#pragma unroll
        for (int m = 0; m < 4; m++)
            af[m] = *(const u16x8*)(Ab + (wr * 128 + 64 + m * 16 + l16) * 32 + lhi * 8);
        if (t + 2 < NT) {
            stageB(t + 2);
            asm volatile("s_waitcnt vmcnt(4)" ::: "memory");
        } else if (t == NT - 2) {
            asm volatile("s_waitcnt vmcnt(0)" ::: "memory");
        }
        __builtin_amdgcn_s_barrier();
        __builtin_amdgcn_sched_barrier(0);
        __builtin_amdgcn_s_setprio(1);
#pragma unroll
        for (int m = 0; m < 4; m++)
#pragma unroll
            for (int n = 0; n < 4; n++)
                acc[4 + m][n] = mfma32(af[m], bfr[n], acc[4 + m][n]);
        __builtin_amdgcn_s_setprio(0);
        __builtin_amdgcn_s_barrier();
    }

#pragma unroll
    for (int mi = 0; mi < 8; mi++)
#pragma unroll
        for (int ni = 0; ni < 4; ni++) {
            int row = bm * 256 + wr * 128 + mi * 16 + lhi * 4;
            int col = bn * 256 + wc * 64 + ni * 16 + l16;
            float bv = bias ? bias[col] : 0.f;
#pragma unroll
            for (int j = 0; j < 4; j++) {
                float v = acc[mi][ni][j] + bv;
                size_t idx = (size_t)(row + j) * N + col;
                if constexpr (MODE == 0) {
                    ((float*)Cout)[idx] = v;
                } else if constexpr (MODE == 1) {
                    ((unsigned short*)Cout)[idx] = f2bf(v);
                } else {
                    ((unsigned short*)Cout)[idx] = f2bf(v > 0.f ? v : 0.f);
                }
            }
        }
}

// ---------------- flash attention (causal), 64 q-rows/block, fused qkv input ----------------
__global__ __launch_bounds__(256, 2) void attn_fwd(
    const unsigned short* __restrict__ qkv, unsigned short* __restrict__ ctxb)
{
    __shared__ unsigned short Ks[64 * 72];
    __shared__ unsigned short Vs[64 * 72];   // transposed: Vs[d][kv]
    __shared__ unsigned short Ps[4 * 16 * 72];
    const int tid = threadIdx.x;
    const int wid = tid >> 6, lane = tid & 63;
    const int l16 = lane & 15, lhi = lane >> 4;
    const int bh  = blockIdx.y, b = bh >> 4, h = bh & 15;
    const int q0  = blockIdx.x * 64;
    const size_t rowbase = (size_t)b * SEQ;

    const int qrow = q0 + wid * 16 + l16;
    const unsigned short* qp = qkv + (rowbase + qrow) * QKV_N + h * HDIM + lhi * 8;
    u16x8 qf0 = *(const u16x8*)qp;
    u16x8 qf1 = *(const u16x8*)(qp + 32);

    f32x4 oa[4];
    float mj[4], lj[4];
#pragma unroll
    for (int i = 0; i < 4; i++) {
        oa[i] = (f32x4){0.f, 0.f, 0.f, 0.f};
        mj[i] = -1e30f; lj[i] = 0.f;
    }

    const int ntiles = blockIdx.x + 1;
    for (int kt = 0; kt < ntiles; ++kt) {
        const int kv0 = kt * 64;
        __syncthreads();
#pragma unroll
        for (int it = 0; it < 2; ++it) {
            int e = it * 256 + tid;
            int r = e >> 3, d0 = (e & 7) * 8;
            size_t goff = (rowbase + kv0 + r) * QKV_N + D_MODEL + h * HDIM + d0;
            u16x8 kk = *(const u16x8*)(qkv + goff);
            *(u16x8*)(&Ks[r * 72 + d0]) = kk;
            u16x8 vv = *(const u16x8*)(qkv + goff + D_MODEL);
#pragma unroll
            for (int j = 0; j < 8; j++) Vs[(d0 + j) * 72 + r] = vv[j];
        }
        __syncthreads();

        f32x4 sa[4];
#pragma unroll
        for (int ni = 0; ni < 4; ni++) {
            f32x4 z = (f32x4){0.f, 0.f, 0.f, 0.f};
            u16x8 k0f = *(const u16x8*)(&Ks[(ni * 16 + l16) * 72 + lhi * 8]);
            u16x8 k1f = *(const u16x8*)(&Ks[(ni * 16 + l16) * 72 + 32 + lhi * 8]);
            z = mfma32(qf0, k0f, z);
            z = mfma32(qf1, k1f, z);
            sa[ni] = z;
        }
        float tm[4] = {-1e30f, -1e30f, -1e30f, -1e30f};
#pragma unroll
        for (int ni = 0; ni < 4; ni++)
#pragma unroll
            for (int j = 0; j < 4; j++) {
                float v = sa[ni][j] * 0.125f;
                int row = q0 + wid * 16 + lhi * 4 + j;
                int col = kv0 + ni * 16 + l16;
                if (col > row) v = -1e30f;
                sa[ni][j] = v;
                tm[j] = fmaxf(tm[j], v);
            }
#pragma unroll
        for (int j = 0; j < 4; j++) {
#pragma unroll
            for (int off = 1; off < 16; off <<= 1)
                tm[j] = fmaxf(tm[j], __shfl_xor(tm[j], off));
        }
        float al[4], rs[4] = {0.f, 0.f, 0.f, 0.f};
#pragma unroll
        for (int j = 0; j < 4; j++) {
            float mn = fmaxf(mj[j], tm[j]);
            al[j] = __expf(mj[j] - mn);
            mj[j] = mn;
        }
#pragma unroll
        for (int ni = 0; ni < 4; ni++)
#pragma unroll
            for (int j = 0; j < 4; j++) {
                float p = __expf(sa[ni][j] - mj[j]);
                rs[j] += p;
                Ps[wid * 1152 + (lhi * 4 + j) * 72 + ni * 16 + l16] = f2bf(p);
            }
#pragma unroll
        for (int j = 0; j < 4; j++) {
#pragma unroll
            for (int off = 1; off < 16; off <<= 1)
                rs[j] += __shfl_xor(rs[j], off);
            lj[j] = lj[j] * al[j] + rs[j];
        }
#pragma unroll
        for (int di = 0; di < 4; di++)
#pragma unroll
            for (int j = 0; j < 4; j++) oa[di][j] *= al[j];
#pragma unroll
        for (int di = 0; di < 4; di++) {
#pragma unroll
            for (int kc = 0; kc < 2; kc++) {
                u16x8 pf = *(const u16x8*)(&Ps[wid * 1152 + l16 * 72 + kc * 32 + lhi * 8]);
                u16x8 vf = *(const u16x8*)(&Vs[(di * 16 + l16) * 72 + kc * 32 + lhi * 8]);
                oa[di] = mfma32(pf, vf, oa[di]);
            }
        }
    }
#pragma unroll
    for (int di = 0; di < 4; di++)
#pragma unroll
        for (int j = 0; j < 4; j++) {
            int row = q0 + wid * 16 + lhi * 4 + j;
            ctxb[(rowbase + row) * D_MODEL + h * HDIM + di * 16 + l16] =
                f2bf(oa[di][j] / lj[j]);
        }
}

// ---------------- fused residual + LayerNorm ----------------
__global__ __launch_bounds__(256) void ln_fused(
    float* __restrict__ x, const float* __restrict__ tmp,
    const float* __restrict__ sc, const float* __restrict__ bi,
    unsigned short* __restrict__ xb)
{
    const int row = blockIdx.x;
    const int t = threadIdx.x;
    const size_t base = (size_t)row * D_MODEL + t * 4;
    float4 xv = *(const float4*)(x + base);
    float4 tv = *(const float4*)(tmp + base);
    float v0 = xv.x + tv.x, v1 = xv.y + tv.y, v2 = xv.z + tv.z, v3 = xv.w + tv.w;
    float sum = v0 + v1 + v2 + v3;
    float sq  = v0 * v0 + v1 * v1 + v2 * v2 + v3 * v3;
#pragma unroll
    for (int off = 1; off < 64; off <<= 1) {
        sum += __shfl_xor(sum, off);
        sq  += __shfl_xor(sq, off);
    }
    __shared__ float red[8];
    int wid = t >> 6, lane = t & 63;
    if (lane == 0) { red[wid] = sum; red[4 + wid] = sq; }
    __syncthreads();
    sum = red[0] + red[1] + red[2] + red[3];
    sq  = red[4] + red[5] + red[6] + red[7];
    float mu   = sum * (1.f / D_MODEL);
    float var  = sq * (1.f / D_MODEL) - mu * mu;
    float rstd = rsqrtf(var + LN_EPS);
    int c = t * 4;
    float4 sv = *(const float4*)(sc + c);
    float4 bv = *(const float4*)(bi + c);
    float y0 = sv.x * (v0 - mu) * rstd + bv.x;
    float y1 = sv.y * (v1 - mu) * rstd + bv.y;
    float y2 = sv.z * (v2 - mu) * rstd + bv.z;
    float y3 = sv.w * (v3 - mu) * rstd + bv.w;
    *(float4*)(x + base) = make_float4(y0, y1, y2, y3);
    unsigned long long pk = (unsigned long long)f2bf(y0)
        | ((unsigned long long)f2bf(y1) << 16)
        | ((unsigned long long)f2bf(y2) << 32)
        | ((unsigned long long)f2bf(y3) << 48);
    *(unsigned long long*)(xb + base) = pk;
}

// ---------------- launcher ----------------
extern "C" void kernel_launch(void* const* d_in, const int* in_sizes, int n_in,
                              void* d_out, int out_size, void* d_ws, size_t ws_size,
                              hipStream_t stream)
{
    (void)in_sizes; (void)n_in; (void)out_size;
    const int*   tokens = (const int*)d_in[0];
    const float* emb  = (const float*)d_in[2];
    const float* pose = (const float*)d_in[3];
    const float* Wq = (const float*)d_in[4];
    const float* bq = (const float*)d_in[5];
    const float* Wk = (const float*)d_in[6];
    const float* bk = (const float*)d_in[7];
    const float* Wv = (const float*)d_in[8];
    const float* bv = (const float*)d_in[9];
    const float* Wo = (const float*)d_in[10];
    const float* bo = (const float*)d_in[11];
    const float* n1s = (const float*)d_in[12];
    const float* n1b = (const float*)d_in[13];
    const float* W1 = (const float*)d_in[14];
    const float* b1 = (const float*)d_in[15];
    const float* W2 = (const float*)d_in[16];
    const float* b2 = (const float*)d_in[17];
    const float* n2s = (const float*)d_in[18];
    const float* n2b = (const float*)d_in[19];

    char* w = (char*)d_ws;
    size_t off = 0;
    auto carve = [&](size_t bytes) -> void* {
        void* p = w + off;
        off = (off + bytes + 255) & ~(size_t)255;
        return p;
    };
    float* x   = (float*)carve((size_t)ROWS * D_MODEL * 4);
    float* tmp = (float*)carve((size_t)ROWS * D_MODEL * 4);
    unsigned short* xb    = (unsigned short*)carve((size_t)ROWS * D_MODEL * 2);
    unsigned short* qkvb  = (unsigned short*)carve((size_t)ROWS * QKV_N * 2);
    unsigned short* cbuf  = (unsigned short*)carve((size_t)ROWS * D_MODEL * 2);
    unsigned short* hbuf  = (unsigned short*)carve((size_t)ROWS * FF_DIM * 2);
    unsigned short* wt    = (unsigned short*)carve((size_t)D_MODEL * FF_DIM * 2);
    float* bqkv = (float*)carve((size_t)NLAYER * QKV_N * 4);
    // tied-head emb (bf16) aliases qkvb+cbuf+hbuf (dead by then): 65.5MB < 67.2MB
    unsigned short* embb = qkvb;
    if (off > ws_size) return;  // ws too small: fail visibly, no corruption

    bias3_k<<<NLAYER * 3, 256, 0, stream>>>(bq, bk, bv, bqkv);
    embed_k<<<ROWS, 256, 0, stream>>>(tokens, emb, pose, x, xb);

    for (int l = 0; l < NLAYER; l++) {
        const float* Wq_l = Wq + (size_t)l * D_MODEL * D_MODEL;
        const float* Wk_l = Wk + (size_t)l * D_MODEL * D_MODEL;
        const float* Wv_l = Wv + (size_t)l * D_MODEL * D_MODEL;
        const float* Wo_l = Wo + (size_t)l * D_MODEL * D_MODEL;
        const float* W1_l = W1 + (size_t)l * D_MODEL * FF_DIM;
        const float* W2_l = W2 + (size_t)l * FF_DIM * D_MODEL;

        // fused QKV: wt rows [0,1024)=Wq^T, [1024,2048)=Wk^T, [2048,3072)=Wv^T
        transpose_cast<<<dim3(16, 16), 256, 0, stream>>>(Wq_l, wt, D_MODEL, D_MODEL);
        transpose_cast<<<dim3(16, 16), 256, 0, stream>>>(Wk_l, wt + 1024 * 1024, D_MODEL, D_MODEL);
        transpose_cast<<<dim3(16, 16), 256, 0, stream>>>(Wv_l, wt + 2 * 1024 * 1024, D_MODEL, D_MODEL);
        gemm256<1><<<(QKV_N / 256) * 16, 512, 0, stream>>>(xb, wt, bqkv + (size_t)l * QKV_N, qkvb, QKV_N, D_MODEL);

        attn_fwd<<<dim3(SEQ / 64, BATCH * NHEAD), 256, 0, stream>>>(qkvb, cbuf);

        transpose_cast<<<dim3(16, 16), 256, 0, stream>>>(Wo_l, wt, D_MODEL, D_MODEL);
        gemm_bt<0><<<8 * 32, 256, 0, stream>>>(cbuf, wt, bo + (size_t)l * D_MODEL, tmp, D_MODEL, D_MODEL);
        ln_fused<<<ROWS, 256, 0, stream>>>(x, tmp, n1s + (size_t)l * D_MODEL, n1b + (size_t)l * D_MODEL, xb);

        transpose_cast<<<dim3(64, 16), 256, 0, stream>>>(W1_l, wt, D_MODEL, FF_DIM);
        gemm256<2><<<(FF_DIM / 256) * 16, 512, 0, stream>>>(xb, wt, b1 + (size_t)l * FF_DIM, hbuf, FF_DIM, D_MODEL);
        transpose_cast<<<dim3(16, 64), 256, 0, stream>>>(W2_l, wt, FF_DIM, D_MODEL);
        gemm_bt<0><<<8 * 32, 256, 0, stream>>>(hbuf, wt, b2 + (size_t)l * D_MODEL, tmp, D_MODEL, FF_DIM);
        ln_fused<<<ROWS, 256, 0, stream>>>(x, tmp, n2s + (size_t)l * D_MODEL, n2b + (size_t)l * D_MODEL, xb);
    }

    cast_bf<<<(VOCAB * D_MODEL) / 1024, 256, 0, stream>>>(emb, embb, (size_t)VOCAB * D_MODEL);
    gemm256<0><<<(VOCAB / 256) * 16, 512, 0, stream>>>(xb, embb, nullptr, d_out, VOCAB, D_MODEL);
}

// Round 4
// 2834.988 us; speedup vs baseline: 1.2127x; 1.0390x over previous
//
#include <hip/hip_runtime.h>

#define D_MODEL 1024
#define SEQ     1024
#define BATCH   4
#define NHEAD   16
#define HDIM    64
#define FF_DIM  4096
#define NLAYER  8
#define VOCAB   32000
#define ROWS    (BATCH*SEQ)
#define QKV_N   3072
#define LN_EPS  1e-5f

typedef __attribute__((ext_vector_type(4))) float   f32x4;
typedef __attribute__((ext_vector_type(8))) unsigned short u16x8;
typedef __attribute__((ext_vector_type(8))) __bf16  bf16x8;

typedef const unsigned int __attribute__((address_space(1)))* gas_t;
typedef unsigned int __attribute__((address_space(3)))* las_t;

__device__ __forceinline__ void gld16(const void* g, void* l) {
    __builtin_amdgcn_global_load_lds((gas_t)g, (las_t)l, 16, 0, 0);
}

__device__ __forceinline__ unsigned short f2bf(float f) {
    unsigned int u = __builtin_bit_cast(unsigned int, f);
    u += 0x7FFFu + ((u >> 16) & 1u);   // RNE
    return (unsigned short)(u >> 16);
}

__device__ __forceinline__ f32x4 mfma32(u16x8 a, u16x8 b, f32x4 c) {
    return __builtin_amdgcn_mfma_f32_16x16x32_bf16(
        __builtin_bit_cast(bf16x8, a), __builtin_bit_cast(bf16x8, b), c, 0, 0, 0);
}

// ---------------- embed: x = emb[tok] + pos ----------------
__global__ __launch_bounds__(256) void embed_k(
    const int* __restrict__ tok, const float* __restrict__ emb,
    const float* __restrict__ pos, float* __restrict__ x,
    unsigned short* __restrict__ xb)
{
    int bs = blockIdx.x;
    int s  = bs & (SEQ - 1);
    int tk = tok[bs];
    int c  = threadIdx.x * 4;
    float4 e = *(const float4*)(emb + (size_t)tk * D_MODEL + c);
    float4 p = *(const float4*)(pos + (size_t)s * D_MODEL + c);
    float y0 = e.x + p.x, y1 = e.y + p.y, y2 = e.z + p.z, y3 = e.w + p.w;
    size_t base = (size_t)bs * D_MODEL + c;
    *(float4*)(x + base) = make_float4(y0, y1, y2, y3);
    unsigned long long pk = (unsigned long long)f2bf(y0)
        | ((unsigned long long)f2bf(y1) << 16)
        | ((unsigned long long)f2bf(y2) << 32)
        | ((unsigned long long)f2bf(y3) << 48);
    *(unsigned long long*)(xb + base) = pk;
}

// ---------------- cast fp32 -> bf16 ----------------
__global__ __launch_bounds__(256) void cast_bf(
    const float* __restrict__ in, unsigned short* __restrict__ out, size_t n)
{
    size_t i = ((size_t)blockIdx.x * 256 + threadIdx.x) * 4;
    if (i >= n) return;
    float4 v = *(const float4*)(in + i);
    unsigned long long pk = (unsigned long long)f2bf(v.x)
        | ((unsigned long long)f2bf(v.y) << 16)
        | ((unsigned long long)f2bf(v.z) << 32)
        | ((unsigned long long)f2bf(v.w) << 48);
    *(unsigned long long*)(out + i) = pk;
}

// ---------------- concat qkv biases ----------------
__global__ __launch_bounds__(256) void bias3_k(
    const float* __restrict__ bq, const float* __restrict__ bk,
    const float* __restrict__ bv, float* __restrict__ out)
{
    int l = blockIdx.x / 3, which = blockIdx.x % 3;
    const float* src = which == 0 ? bq : (which == 1 ? bk : bv);
    int i = threadIdx.x * 4;
    float4 v = *(const float4*)(src + (size_t)l * D_MODEL + i);
    *(float4*)(out + (size_t)l * QKV_N + which * D_MODEL + i) = v;
}

// ---------------- W [K,N] fp32 -> Wt [N,K] bf16, 64x64 tiles ----------------
__global__ __launch_bounds__(256) void transpose_cast(
    const float* __restrict__ W, unsigned short* __restrict__ Wt, int K, int N)
{
    __shared__ float t[64][65];
    int n0 = blockIdx.x * 64, k0 = blockIdx.y * 64;
    int rr = threadIdx.x >> 4;          // 0..15
    int cc = (threadIdx.x & 15) * 4;    // 0..60
#pragma unroll
    for (int it = 0; it < 4; it++) {
        int r = it * 16 + rr;
        float4 v = *(const float4*)(W + (size_t)(k0 + r) * N + n0 + cc);
        t[r][cc] = v.x; t[r][cc + 1] = v.y; t[r][cc + 2] = v.z; t[r][cc + 3] = v.w;
    }
    __syncthreads();
#pragma unroll
    for (int it = 0; it < 4; it++) {
        int n = it * 16 + rr;
        unsigned long long pk = (unsigned long long)f2bf(t[cc][n])
            | ((unsigned long long)f2bf(t[cc + 1][n]) << 16)
            | ((unsigned long long)f2bf(t[cc + 2][n]) << 32)
            | ((unsigned long long)f2bf(t[cc + 3][n]) << 48);
        *(unsigned long long*)(Wt + (size_t)(n0 + n) * K + k0 + cc) = pk;
    }
}

// ---------------- small NT GEMM (m97 128x128), for N=1024 outputs ----------------
template<int MODE>
__global__ __launch_bounds__(256, 3) void gemm_bt(
    const unsigned short* __restrict__ A, const unsigned short* __restrict__ Bt,
    const float* __restrict__ bias, void* __restrict__ Cout, int N, int K)
{
    __shared__ unsigned short As[128 * 32];
    __shared__ unsigned short Bs[128 * 32];
    int flat = blockIdx.x;
    const int bm = flat & 31, bn = flat >> 5;
    const int tid  = threadIdx.x;
    const int wid  = tid >> 6, lane = tid & 63;
    const int l16  = lane & 15, lhi = lane >> 4;
    const int wr   = wid >> 1, wc = wid & 1;

    const int srow = wid * 32 + (lane >> 2);
    const int scol = (lane & 3) * 8;
    const unsigned short* gA0 = A  + ((size_t)bm * 128 + srow) * K + scol;
    const unsigned short* gB0 = Bt + ((size_t)bn * 128 + srow) * K + scol;
    unsigned short* lA = As + wid * 32 * 32;
    unsigned short* lB = Bs + wid * 32 * 32;

    f32x4 acc[4][4];
#pragma unroll
    for (int i = 0; i < 4; i++)
#pragma unroll
        for (int j = 0; j < 4; j++) acc[i][j] = (f32x4){0.f, 0.f, 0.f, 0.f};

    for (int k0 = 0; k0 < K; k0 += 32) {
        __syncthreads();
        gld16(gA0 + k0,                  lA);
        gld16(gA0 + k0 + 16 * (size_t)K, lA + 16 * 32);
        gld16(gB0 + k0,                  lB);
        gld16(gB0 + k0 + 16 * (size_t)K, lB + 16 * 32);
        __syncthreads();
        u16x8 af[4], bfr[4];
#pragma unroll
        for (int i = 0; i < 4; i++)
            af[i] = *(const u16x8*)(As + (wr * 64 + i * 16 + l16) * 32 + lhi * 8);
#pragma unroll
        for (int i = 0; i < 4; i++)
            bfr[i] = *(const u16x8*)(Bs + (wc * 64 + i * 16 + l16) * 32 + lhi * 8);
#pragma unroll
        for (int mi = 0; mi < 4; mi++)
#pragma unroll
            for (int ni = 0; ni < 4; ni++)
                acc[mi][ni] = mfma32(af[mi], bfr[ni], acc[mi][ni]);
    }

#pragma unroll
    for (int mi = 0; mi < 4; mi++)
#pragma unroll
        for (int ni = 0; ni < 4; ni++) {
            int row = bm * 128 + wr * 64 + mi * 16 + lhi * 4;
            int col = bn * 128 + wc * 64 + ni * 16 + l16;
            float bv = bias ? bias[col] : 0.f;
#pragma unroll
            for (int j = 0; j < 4; j++) {
                float v = acc[mi][ni][j] + bv;
                size_t idx = (size_t)(row + j) * N + col;
                if constexpr (MODE == 0) {
                    ((float*)Cout)[idx] = v;
                } else if constexpr (MODE == 1) {
                    ((unsigned short*)Cout)[idx] = f2bf(v);
                } else {
                    ((unsigned short*)Cout)[idx] = f2bf(v > 0.f ? v : 0.f);
                }
            }
        }
}

// ================= 256x256 8-phase GEMM (m201 template, plain HIP) =================
// BK=64, 8 waves (2M x 4N), 512 threads, 2 LDS double-buffers (128 KiB total).
// LDS swizzle: phys_byte = linear_byte ^ ((row&7)<<4)  (involution, bits 4-6).
//   - ds_read side: frag rows are m*16+l16 -> row&7 == l16&7 (lane-constant XOR).
//   - stage side: gld16 dest stays LINEAR; the global SOURCE is pre-swizzled
//     per lane (same involution), per rule #21 (both-sides-or-neither).
// Phases per 2 K-tiles (t even -> buf0, t+1 -> buf1):
//   P1: dsA(m0-3)+dsB(n01) | stage A0(t+1) | sync | 16 MFMA | bar
//   P2: dsB(n23)           | stage A1(t+1) | sync | 16 MFMA | bar
//   P3: dsA(m4-7)          | stage B0(t+2) | sync | 16 MFMA | bar
//   P4:                    | stage B1(t+2), vmcnt(4) | sync | 16 MFMA | bar
//   P5-P8: same on buf1, staging A(t+2), B(t+3), vmcnt(4) at P8.
// Induction invariant: entering each iteration exactly B(t+1)'s 4 loads are
// outstanding; vmcnt(4) at P4 completes B(t+1),A(t+1); at P8 completes
// B(t+2),A(t+2). Never drains to 0 mid-loop (T4).

#define PSYNC() do { __builtin_amdgcn_s_barrier(); \
    asm volatile("s_waitcnt lgkmcnt(0)" ::: "memory"); \
    __builtin_amdgcn_sched_barrier(0); } while (0)
#define PEND() __builtin_amdgcn_s_barrier()

#define LOADA(reg, half) do { \
    _Pragma("unroll") \
    for (int m_ = 0; m_ < 4; m_++) { \
        aF[m_][0] = *(const u16x8*)((reg) + ((half)*4 + m_) * 2048 + lane0); \
        aF[m_][1] = *(const u16x8*)((reg) + ((half)*4 + m_) * 2048 + lane1); \
    } } while (0)

#define LOADB(reg, np) do { \
    _Pragma("unroll") \
    for (int n_ = 0; n_ < 2; n_++) { \
        bF[(np)*2 + n_][0] = *(const u16x8*)((reg) + ((np)*2 + n_) * 2048 + lane0); \
        bF[(np)*2 + n_][1] = *(const u16x8*)((reg) + ((np)*2 + n_) * 2048 + lane1); \
    } } while (0)

#define MFMA8(ma, np) do { \
    __builtin_amdgcn_s_setprio(1); \
    _Pragma("unroll") \
    for (int m_ = 0; m_ < 4; m_++) \
        _Pragma("unroll") \
        for (int n_ = 0; n_ < 2; n_++) { \
            acc[(ma)+m_][(np)*2+n_] = mfma32(aF[m_][0], bF[(np)*2+n_][0], acc[(ma)+m_][(np)*2+n_]); \
            acc[(ma)+m_][(np)*2+n_] = mfma32(aF[m_][1], bF[(np)*2+n_][1], acc[(ma)+m_][(np)*2+n_]); \
        } \
    __builtin_amdgcn_s_setprio(0); \
} while (0)

template<int MODE>
__global__ __launch_bounds__(512, 2) void gemm256(
    const unsigned short* __restrict__ A, const unsigned short* __restrict__ Bt,
    const float* __restrict__ bias, void* __restrict__ Cout, int N, int K)
{
    __shared__ unsigned short lds[65536] __attribute__((aligned(128)));
    const int tid = threadIdx.x, wid = tid >> 6, lane = tid & 63;
    const int l16 = lane & 15, lhi = lane >> 4;
    const int wr = wid >> 2, wc = wid & 3;

    int flat = blockIdx.x;
    { int cpx = gridDim.x >> 3; flat = (flat & 7) * cpx + (flat >> 3); }
    const int bm = flat & 15, bn = flat >> 4;
    const int NT = K >> 6;

    // ---- staging: thread covers phys bytes [tid*16, tid*16+16) of a half
    // (per sweep).  row = tid>>3 (+64 for sweep 1); source col pre-swizzled.
    const int srowL = tid >> 3;                                      // 0..63
    const int scolb = ((tid & 7) << 4) ^ (((tid >> 3) & 7) << 4);    // bytes
    const unsigned short* baseA = A  + (size_t)(bm * 256 + srowL) * K + (scolb >> 1);
    const unsigned short* baseB = Bt + (size_t)(bn * 256 + srowL) * K + (scolb >> 1);
    unsigned short* dst0 = lds + wid * 512;   // wave-uniform; HW adds lane*16B

    auto stage = [&](int isB, int tile, int h) {   // one half-tile = 2 gld16
        const unsigned short* s = (isB ? baseB : baseA) + (size_t)(h * 128) * K + tile * 64;
        unsigned short* d = dst0 + (tile & 1) * 32768 + isB * 16384 + h * 8192;
        gld16(s, d);
        gld16(s + (size_t)64 * K, d + 4096);
    };

    // ---- frag-read lane offsets (bytes), swizzle folded in
    const int lswz  = (l16 & 7) << 4;
    const int lane0 = ((lhi * 16) ^ lswz) + l16 * 128;        // k-substep 0
    const int lane1 = ((64 + lhi * 16) ^ lswz) + l16 * 128;   // k-substep 1

    const char* aR0 = (const char*)lds + wr * 16384;
    const char* bR0 = (const char*)lds + 32768 + (wc >> 1) * 16384 + (wc & 1) * 8192;
    const char* aR1 = aR0 + 65536;
    const char* bR1 = bR0 + 65536;

    f32x4 acc[8][4];
#pragma unroll
    for (int i = 0; i < 8; i++)
#pragma unroll
        for (int j = 0; j < 4; j++) acc[i][j] = (f32x4){0.f, 0.f, 0.f, 0.f};
    u16x8 aF[4][2], bF[4][2];

    // prologue: B(0),A(0),B(1) staged; leave B(1) in flight
    stage(1, 0, 0); stage(1, 0, 1); stage(0, 0, 0); stage(0, 0, 1);
    stage(1, 1, 0); stage(1, 1, 1);
    asm volatile("s_waitcnt vmcnt(4)" ::: "memory");
    __builtin_amdgcn_s_barrier();

    for (int t = 0; t < NT; t += 2) {
        const bool more = (t + 2) < NT;
        // ---------- K-tile t (buf0) ----------
        LOADA(aR0, 0); LOADB(bR0, 0);
        stage(0, t + 1, 0);
        PSYNC(); MFMA8(0, 0); PEND();

        LOADB(bR0, 1);
        stage(0, t + 1, 1);
        PSYNC(); MFMA8(0, 1); PEND();

        LOADA(aR0, 1);
        if (more) stage(1, t + 2, 0);
        PSYNC(); MFMA8(4, 0); PEND();

        if (more) { stage(1, t + 2, 1); asm volatile("s_waitcnt vmcnt(4)" ::: "memory"); }
        else      { asm volatile("s_waitcnt vmcnt(0)" ::: "memory"); }
        PSYNC(); MFMA8(4, 1); PEND();

        // ---------- K-tile t+1 (buf1) ----------
        LOADA(aR1, 0); LOADB(bR1, 0);
        if (more) stage(0, t + 2, 0);
        PSYNC(); MFMA8(0, 0); PEND();

        LOADB(bR1, 1);
        if (more) stage(0, t + 2, 1);
        PSYNC(); MFMA8(0, 1); PEND();

        LOADA(aR1, 1);
        if (more) stage(1, t + 3, 0);
        PSYNC(); MFMA8(4, 0); PEND();

        if (more) { stage(1, t + 3, 1); asm volatile("s_waitcnt vmcnt(4)" ::: "memory"); }
        PSYNC(); MFMA8(4, 1); PEND();
    }

#pragma unroll
    for (int mi = 0; mi < 8; mi++)
#pragma unroll
        for (int ni = 0; ni < 4; ni++) {
            int row = bm * 256 + wr * 128 + mi * 16 + lhi * 4;
            int col = bn * 256 + wc * 64 + ni * 16 + l16;
            float bv = bias ? bias[col] : 0.f;
#pragma unroll
            for (int j = 0; j < 4; j++) {
                float v = acc[mi][ni][j] + bv;
                size_t idx = (size_t)(row + j) * N + col;
                if constexpr (MODE == 0) {
                    ((float*)Cout)[idx] = v;
                } else if constexpr (MODE == 1) {
                    ((unsigned short*)Cout)[idx] = f2bf(v);
                } else {
                    ((unsigned short*)Cout)[idx] = f2bf(v > 0.f ? v : 0.f);
                }
            }
        }
}

// ---------------- flash attention (causal), 64 q-rows/block, fused qkv input ----------------
__global__ __launch_bounds__(256, 2) void attn_fwd(
    const unsigned short* __restrict__ qkv, unsigned short* __restrict__ ctxb)
{
    __shared__ unsigned short Ks[64 * 72];
    __shared__ unsigned short Vs[64 * 72];   // transposed: Vs[d][kv]
    __shared__ unsigned short Ps[4 * 16 * 72];
    const int tid = threadIdx.x;
    const int wid = tid >> 6, lane = tid & 63;
    const int l16 = lane & 15, lhi = lane >> 4;
    const int bh  = blockIdx.y, b = bh >> 4, h = bh & 15;
    const int q0  = blockIdx.x * 64;
    const size_t rowbase = (size_t)b * SEQ;

    const int qrow = q0 + wid * 16 + l16;
    const unsigned short* qp = qkv + (rowbase + qrow) * QKV_N + h * HDIM + lhi * 8;
    u16x8 qf0 = *(const u16x8*)qp;
    u16x8 qf1 = *(const u16x8*)(qp + 32);

    f32x4 oa[4];
    float mj[4], lj[4];
#pragma unroll
    for (int i = 0; i < 4; i++) {
        oa[i] = (f32x4){0.f, 0.f, 0.f, 0.f};
        mj[i] = -1e30f; lj[i] = 0.f;
    }

    const int ntiles = blockIdx.x + 1;
    for (int kt = 0; kt < ntiles; ++kt) {
        const int kv0 = kt * 64;
        __syncthreads();
#pragma unroll
        for (int it = 0; it < 2; ++it) {
            int e = it * 256 + tid;
            int r = e >> 3, d0 = (e & 7) * 8;
            size_t goff = (rowbase + kv0 + r) * QKV_N + D_MODEL + h * HDIM + d0;
            u16x8 kk = *(const u16x8*)(qkv + goff);
            *(u16x8*)(&Ks[r * 72 + d0]) = kk;
            u16x8 vv = *(const u16x8*)(qkv + goff + D_MODEL);
#pragma unroll
            for (int j = 0; j < 8; j++) Vs[(d0 + j) * 72 + r] = vv[j];
        }
        __syncthreads();

        f32x4 sa[4];
#pragma unroll
        for (int ni = 0; ni < 4; ni++) {
            f32x4 z = (f32x4){0.f, 0.f, 0.f, 0.f};
            u16x8 k0f = *(const u16x8*)(&Ks[(ni * 16 + l16) * 72 + lhi * 8]);
            u16x8 k1f = *(const u16x8*)(&Ks[(ni * 16 + l16) * 72 + 32 + lhi * 8]);
            z = mfma32(qf0, k0f, z);
            z = mfma32(qf1, k1f, z);
            sa[ni] = z;
        }
        float tm[4] = {-1e30f, -1e30f, -1e30f, -1e30f};
#pragma unroll
        for (int ni = 0; ni < 4; ni++)
#pragma unroll
            for (int j = 0; j < 4; j++) {
                float v = sa[ni][j] * 0.125f;
                int row = q0 + wid * 16 + lhi * 4 + j;
                int col = kv0 + ni * 16 + l16;
                if (col > row) v = -1e30f;
                sa[ni][j] = v;
                tm[j] = fmaxf(tm[j], v);
            }
#pragma unroll
        for (int j = 0; j < 4; j++) {
#pragma unroll
            for (int off = 1; off < 16; off <<= 1)
                tm[j] = fmaxf(tm[j], __shfl_xor(tm[j], off));
        }
        float al[4], rs[4] = {0.f, 0.f, 0.f, 0.f};
#pragma unroll
        for (int j = 0; j < 4; j++) {
            float mn = fmaxf(mj[j], tm[j]);
            al[j] = __expf(mj[j] - mn);
            mj[j] = mn;
        }
#pragma unroll
        for (int ni = 0; ni < 4; ni++)
#pragma unroll
            for (int j = 0; j < 4; j++) {
                float p = __expf(sa[ni][j] - mj[j]);
                rs[j] += p;
                Ps[wid * 1152 + (lhi * 4 + j) * 72 + ni * 16 + l16] = f2bf(p);
            }
#pragma unroll
        for (int j = 0; j < 4; j++) {
#pragma unroll
            for (int off = 1; off < 16; off <<= 1)
                rs[j] += __shfl_xor(rs[j], off);
            lj[j] = lj[j] * al[j] + rs[j];
        }
#pragma unroll
        for (int di = 0; di < 4; di++)
#pragma unroll
            for (int j = 0; j < 4; j++) oa[di][j] *= al[j];
#pragma unroll
        for (int di = 0; di < 4; di++) {
#pragma unroll
            for (int kc = 0; kc < 2; kc++) {
                u16x8 pf = *(const u16x8*)(&Ps[wid * 1152 + l16 * 72 + kc * 32 + lhi * 8]);
                u16x8 vf = *(const u16x8*)(&Vs[(di * 16 + l16) * 72 + kc * 32 + lhi * 8]);
                oa[di] = mfma32(pf, vf, oa[di]);
            }
        }
    }
#pragma unroll
    for (int di = 0; di < 4; di++)
#pragma unroll
        for (int j = 0; j < 4; j++) {
            int row = q0 + wid * 16 + lhi * 4 + j;
            ctxb[(rowbase + row) * D_MODEL + h * HDIM + di * 16 + l16] =
                f2bf(oa[di][j] / lj[j]);
        }
}

// ---------------- fused residual + LayerNorm ----------------
__global__ __launch_bounds__(256) void ln_fused(
    float* __restrict__ x, const float* __restrict__ tmp,
    const float* __restrict__ sc, const float* __restrict__ bi,
    unsigned short* __restrict__ xb)
{
    const int row = blockIdx.x;
    const int t = threadIdx.x;
    const size_t base = (size_t)row * D_MODEL + t * 4;
    float4 xv = *(const float4*)(x + base);
    float4 tv = *(const float4*)(tmp + base);
    float v0 = xv.x + tv.x, v1 = xv.y + tv.y, v2 = xv.z + tv.z, v3 = xv.w + tv.w;
    float sum = v0 + v1 + v2 + v3;
    float sq  = v0 * v0 + v1 * v1 + v2 * v2 + v3 * v3;
#pragma unroll
    for (int off = 1; off < 64; off <<= 1) {
        sum += __shfl_xor(sum, off);
        sq  += __shfl_xor(sq, off);
    }
    __shared__ float red[8];
    int wid = t >> 6, lane = t & 63;
    if (lane == 0) { red[wid] = sum; red[4 + wid] = sq; }
    __syncthreads();
    sum = red[0] + red[1] + red[2] + red[3];
    sq  = red[4] + red[5] + red[6] + red[7];
    float mu   = sum * (1.f / D_MODEL);
    float var  = sq * (1.f / D_MODEL) - mu * mu;
    float rstd = rsqrtf(var + LN_EPS);
    int c = t * 4;
    float4 sv = *(const float4*)(sc + c);
    float4 bv = *(const float4*)(bi + c);
    float y0 = sv.x * (v0 - mu) * rstd + bv.x;
    float y1 = sv.y * (v1 - mu) * rstd + bv.y;
    float y2 = sv.z * (v2 - mu) * rstd + bv.z;
    float y3 = sv.w * (v3 - mu) * rstd + bv.w;
    *(float4*)(x + base) = make_float4(y0, y1, y2, y3);
    unsigned long long pk = (unsigned long long)f2bf(y0)
        | ((unsigned long long)f2bf(y1) << 16)
        | ((unsigned long long)f2bf(y2) << 32)
        | ((unsigned long long)f2bf(y3) << 48);
    *(unsigned long long*)(xb + base) = pk;
}

// ---------------- launcher ----------------
extern "C" void kernel_launch(void* const* d_in, const int* in_sizes, int n_in,
                              void* d_out, int out_size, void* d_ws, size_t ws_size,
                              hipStream_t stream)
{
    (void)in_sizes; (void)n_in; (void)out_size;
    const int*   tokens = (const int*)d_in[0];
    const float* emb  = (const float*)d_in[2];
    const float* pose = (const float*)d_in[3];
    const float* Wq = (const float*)d_in[4];
    const float* bq = (const float*)d_in[5];
    const float* Wk = (const float*)d_in[6];
    const float* bk = (const float*)d_in[7];
    const float* Wv = (const float*)d_in[8];
    const float* bv = (const float*)d_in[9];
    const float* Wo = (const float*)d_in[10];
    const float* bo = (const float*)d_in[11];
    const float* n1s = (const float*)d_in[12];
    const float* n1b = (const float*)d_in[13];
    const float* W1 = (const float*)d_in[14];
    const float* b1 = (const float*)d_in[15];
    const float* W2 = (const float*)d_in[16];
    const float* b2 = (const float*)d_in[17];
    const float* n2s = (const float*)d_in[18];
    const float* n2b = (const float*)d_in[19];

    char* w = (char*)d_ws;
    size_t off = 0;
    auto carve = [&](size_t bytes) -> void* {
        void* p = w + off;
        off = (off + bytes + 255) & ~(size_t)255;
        return p;
    };
    float* x   = (float*)carve((size_t)ROWS * D_MODEL * 4);
    float* tmp = (float*)carve((size_t)ROWS * D_MODEL * 4);
    unsigned short* xb    = (unsigned short*)carve((size_t)ROWS * D_MODEL * 2);
    unsigned short* qkvb  = (unsigned short*)carve((size_t)ROWS * QKV_N * 2);
    unsigned short* cbuf  = (unsigned short*)carve((size_t)ROWS * D_MODEL * 2);
    unsigned short* hbuf  = (unsigned short*)carve((size_t)ROWS * FF_DIM * 2);
    unsigned short* wt    = (unsigned short*)carve((size_t)D_MODEL * FF_DIM * 2);
    float* bqkv = (float*)carve((size_t)NLAYER * QKV_N * 4);
    unsigned short* embb = qkvb;   // tied-head emb aliases dead qkv/ctx/h region
    if (off > ws_size) return;

    bias3_k<<<NLAYER * 3, 256, 0, stream>>>(bq, bk, bv, bqkv);
    embed_k<<<ROWS, 256, 0, stream>>>(tokens, emb, pose, x, xb);

    for (int l = 0; l < NLAYER; l++) {
        const float* Wq_l = Wq + (size_t)l * D_MODEL * D_MODEL;
        const float* Wk_l = Wk + (size_t)l * D_MODEL * D_MODEL;
        const float* Wv_l = Wv + (size_t)l * D_MODEL * D_MODEL;
        const float* Wo_l = Wo + (size_t)l * D_MODEL * D_MODEL;
        const float* W1_l = W1 + (size_t)l * D_MODEL * FF_DIM;
        const float* W2_l = W2 + (size_t)l * FF_DIM * D_MODEL;

        transpose_cast<<<dim3(16, 16), 256, 0, stream>>>(Wq_l, wt, D_MODEL, D_MODEL);
        transpose_cast<<<dim3(16, 16), 256, 0, stream>>>(Wk_l, wt + 1024 * 1024, D_MODEL, D_MODEL);
        transpose_cast<<<dim3(16, 16), 256, 0, stream>>>(Wv_l, wt + 2 * 1024 * 1024, D_MODEL, D_MODEL);
        gemm256<1><<<(QKV_N / 256) * 16, 512, 0, stream>>>(xb, wt, bqkv + (size_t)l * QKV_N, qkvb, QKV_N, D_MODEL);

        attn_fwd<<<dim3(SEQ / 64, BATCH * NHEAD), 256, 0, stream>>>(qkvb, cbuf);

        transpose_cast<<<dim3(16, 16), 256, 0, stream>>>(Wo_l, wt, D_MODEL, D_MODEL);
        gemm_bt<0><<<8 * 32, 256, 0, stream>>>(cbuf, wt, bo + (size_t)l * D_MODEL, tmp, D_MODEL, D_MODEL);
        ln_fused<<<ROWS, 256, 0, stream>>>(x, tmp, n1s + (size_t)l * D_MODEL, n1b + (size_t)l * D_MODEL, xb);

        transpose_cast<<<dim3(64, 16), 256, 0, stream>>>(W1_l, wt, D_MODEL, FF_DIM);
        gemm256<2><<<(FF_DIM / 256) * 16, 512, 0, stream>>>(xb, wt, b1 + (size_t)l * FF_DIM, hbuf, FF_DIM, D_MODEL);
        transpose_cast<<<dim3(16, 64), 256, 0, stream>>>(W2_l, wt, FF_DIM, D_MODEL);
        gemm_bt<0><<<8 * 32, 256, 0, stream>>>(hbuf, wt, b2 + (size_t)l * D_MODEL, tmp, D_MODEL, FF_DIM);
        ln_fused<<<ROWS, 256, 0, stream>>>(x, tmp, n2s + (size_t)l * D_MODEL, n2b + (size_t)l * D_MODEL, xb);
    }

    cast_bf<<<(VOCAB * D_MODEL) / 1024, 256, 0, stream>>>(emb, embb, (size_t)VOCAB * D_MODEL);
    gemm256<0><<<(VOCAB / 256) * 16, 512, 0, stream>>>(xb, embb, nullptr, d_out, VOCAB, D_MODEL);
}

// Round 5
// 2740.358 us; speedup vs baseline: 1.2545x; 1.0345x over previous
//
#include <hip/hip_runtime.h>

#define D_MODEL 1024
#define SEQ     1024
#define BATCH   4
#define NHEAD   16
#define HDIM    64
#define FF_DIM  4096
#define NLAYER  8
#define VOCAB   32000
#define ROWS    (BATCH*SEQ)
#define QKV_N   3072
#define LN_EPS  1e-5f

typedef __attribute__((ext_vector_type(4))) float   f32x4;
typedef __attribute__((ext_vector_type(8))) unsigned short u16x8;
typedef __attribute__((ext_vector_type(8))) __bf16  bf16x8;

typedef const unsigned int __attribute__((address_space(1)))* gas_t;
typedef unsigned int __attribute__((address_space(3)))* las_t;

__device__ __forceinline__ void gld16(const void* g, void* l) {
    __builtin_amdgcn_global_load_lds((gas_t)g, (las_t)l, 16, 0, 0);
}

__device__ __forceinline__ unsigned short f2bf(float f) {
    unsigned int u = __builtin_bit_cast(unsigned int, f);
    u += 0x7FFFu + ((u >> 16) & 1u);   // RNE
    return (unsigned short)(u >> 16);
}

__device__ __forceinline__ f32x4 mfma32(u16x8 a, u16x8 b, f32x4 c) {
    return __builtin_amdgcn_mfma_f32_16x16x32_bf16(
        __builtin_bit_cast(bf16x8, a), __builtin_bit_cast(bf16x8, b), c, 0, 0, 0);
}

// ---------------- embed: x = emb[tok] + pos ----------------
__global__ __launch_bounds__(256) void embed_k(
    const int* __restrict__ tok, const float* __restrict__ emb,
    const float* __restrict__ pos, float* __restrict__ x,
    unsigned short* __restrict__ xb)
{
    int bs = blockIdx.x;
    int s  = bs & (SEQ - 1);
    int tk = tok[bs];
    int c  = threadIdx.x * 4;
    float4 e = *(const float4*)(emb + (size_t)tk * D_MODEL + c);
    float4 p = *(const float4*)(pos + (size_t)s * D_MODEL + c);
    float y0 = e.x + p.x, y1 = e.y + p.y, y2 = e.z + p.z, y3 = e.w + p.w;
    size_t base = (size_t)bs * D_MODEL + c;
    *(float4*)(x + base) = make_float4(y0, y1, y2, y3);
    unsigned long long pk = (unsigned long long)f2bf(y0)
        | ((unsigned long long)f2bf(y1) << 16)
        | ((unsigned long long)f2bf(y2) << 32)
        | ((unsigned long long)f2bf(y3) << 48);
    *(unsigned long long*)(xb + base) = pk;
}

// ---------------- cast fp32 -> bf16 ----------------
__global__ __launch_bounds__(256) void cast_bf(
    const float* __restrict__ in, unsigned short* __restrict__ out, size_t n)
{
    size_t i = ((size_t)blockIdx.x * 256 + threadIdx.x) * 4;
    if (i >= n) return;
    float4 v = *(const float4*)(in + i);
    unsigned long long pk = (unsigned long long)f2bf(v.x)
        | ((unsigned long long)f2bf(v.y) << 16)
        | ((unsigned long long)f2bf(v.z) << 32)
        | ((unsigned long long)f2bf(v.w) << 48);
    *(unsigned long long*)(out + i) = pk;
}

// ---------------- concat qkv biases ----------------
__global__ __launch_bounds__(256) void bias3_k(
    const float* __restrict__ bq, const float* __restrict__ bk,
    const float* __restrict__ bv, float* __restrict__ out)
{
    int l = blockIdx.x / 3, which = blockIdx.x % 3;
    const float* src = which == 0 ? bq : (which == 1 ? bk : bv);
    int i = threadIdx.x * 4;
    float4 v = *(const float4*)(src + (size_t)l * D_MODEL + i);
    *(float4*)(out + (size_t)l * QKV_N + which * D_MODEL + i) = v;
}

// ---------------- W [K,N] fp32 -> Wt [N,K] bf16, 64x64 tiles ----------------
__global__ __launch_bounds__(256) void transpose_cast(
    const float* __restrict__ W, unsigned short* __restrict__ Wt, int K, int N)
{
    __shared__ float t[64][65];
    int n0 = blockIdx.x * 64, k0 = blockIdx.y * 64;
    int rr = threadIdx.x >> 4;          // 0..15
    int cc = (threadIdx.x & 15) * 4;    // 0..60
#pragma unroll
    for (int it = 0; it < 4; it++) {
        int r = it * 16 + rr;
        float4 v = *(const float4*)(W + (size_t)(k0 + r) * N + n0 + cc);
        t[r][cc] = v.x; t[r][cc + 1] = v.y; t[r][cc + 2] = v.z; t[r][cc + 3] = v.w;
    }
    __syncthreads();
#pragma unroll
    for (int it = 0; it < 4; it++) {
        int n = it * 16 + rr;
        unsigned long long pk = (unsigned long long)f2bf(t[cc][n])
            | ((unsigned long long)f2bf(t[cc + 1][n]) << 16)
            | ((unsigned long long)f2bf(t[cc + 2][n]) << 32)
            | ((unsigned long long)f2bf(t[cc + 3][n]) << 48);
        *(unsigned long long*)(Wt + (size_t)(n0 + n) * K + k0 + cc) = pk;
    }
}

// ---------------- small NT GEMM (m97 128x128) with split-K support ----------------
// grid = (256, P): blockIdx.y = K-part. A cols [y*Klen, (y+1)*Klen) of lda-stride
// rows; Bt likewise. Part y writes Cout + y*ROWS*N. bias added by part 0 only.
template<int MODE>
__global__ __launch_bounds__(256, 3) void gemm_bt(
    const unsigned short* __restrict__ A, int lda,
    const unsigned short* __restrict__ Bt, int ldb,
    const float* __restrict__ bias, void* __restrict__ Cout, int N, int Klen)
{
    __shared__ unsigned short As[128 * 32];
    __shared__ unsigned short Bs[128 * 32];
    const int part = blockIdx.y;
    A  += (size_t)part * Klen;
    Bt += (size_t)part * Klen;
    int flat = blockIdx.x;
    const int bm = flat & 31, bn = flat >> 5;
    const int tid  = threadIdx.x;
    const int wid  = tid >> 6, lane = tid & 63;
    const int l16  = lane & 15, lhi = lane >> 4;
    const int wr   = wid >> 1, wc = wid & 1;

    const int srow = wid * 32 + (lane >> 2);
    const int scol = (lane & 3) * 8;
    const unsigned short* gA0 = A  + ((size_t)bm * 128 + srow) * lda + scol;
    const unsigned short* gB0 = Bt + ((size_t)bn * 128 + srow) * ldb + scol;
    unsigned short* lA = As + wid * 32 * 32;
    unsigned short* lB = Bs + wid * 32 * 32;

    f32x4 acc[4][4];
#pragma unroll
    for (int i = 0; i < 4; i++)
#pragma unroll
        for (int j = 0; j < 4; j++) acc[i][j] = (f32x4){0.f, 0.f, 0.f, 0.f};

    for (int k0 = 0; k0 < Klen; k0 += 32) {
        __syncthreads();
        gld16(gA0 + k0,                    lA);
        gld16(gA0 + k0 + 16 * (size_t)lda, lA + 16 * 32);
        gld16(gB0 + k0,                    lB);
        gld16(gB0 + k0 + 16 * (size_t)ldb, lB + 16 * 32);
        __syncthreads();
        u16x8 af[4], bfr[4];
#pragma unroll
        for (int i = 0; i < 4; i++)
            af[i] = *(const u16x8*)(As + (wr * 64 + i * 16 + l16) * 32 + lhi * 8);
#pragma unroll
        for (int i = 0; i < 4; i++)
            bfr[i] = *(const u16x8*)(Bs + (wc * 64 + i * 16 + l16) * 32 + lhi * 8);
#pragma unroll
        for (int mi = 0; mi < 4; mi++)
#pragma unroll
            for (int ni = 0; ni < 4; ni++)
                acc[mi][ni] = mfma32(af[mi], bfr[ni], acc[mi][ni]);
    }

    const size_t pofs = (size_t)part * (size_t)ROWS * N;
#pragma unroll
    for (int mi = 0; mi < 4; mi++)
#pragma unroll
        for (int ni = 0; ni < 4; ni++) {
            int row = bm * 128 + wr * 64 + mi * 16 + lhi * 4;
            int col = bn * 128 + wc * 64 + ni * 16 + l16;
            float bv = (bias && part == 0) ? bias[col] : 0.f;
#pragma unroll
            for (int j = 0; j < 4; j++) {
                float v = acc[mi][ni][j] + bv;
                size_t idx = pofs + (size_t)(row + j) * N + col;
                if constexpr (MODE == 0) {
                    ((float*)Cout)[idx] = v;
                } else if constexpr (MODE == 1) {
                    ((unsigned short*)Cout)[idx] = f2bf(v);
                } else {
                    ((unsigned short*)Cout)[idx] = f2bf(v > 0.f ? v : 0.f);
                }
            }
        }
}

// ================= 256x256 8-phase GEMM (m201 template, plain HIP) =================
// See R4 notes. This round: peeled epilogue (branch-free steady state).
#define PSYNC() do { __builtin_amdgcn_s_barrier(); \
    asm volatile("s_waitcnt lgkmcnt(0)" ::: "memory"); \
    __builtin_amdgcn_sched_barrier(0); } while (0)
#define PEND() __builtin_amdgcn_s_barrier()
#define VM4()  asm volatile("s_waitcnt vmcnt(4)" ::: "memory")

#define LOADA(reg, half) do { \
    _Pragma("unroll") \
    for (int m_ = 0; m_ < 4; m_++) { \
        aF[m_][0] = *(const u16x8*)((reg) + ((half)*4 + m_) * 2048 + lane0); \
        aF[m_][1] = *(const u16x8*)((reg) + ((half)*4 + m_) * 2048 + lane1); \
    } } while (0)

#define LOADB(reg, np) do { \
    _Pragma("unroll") \
    for (int n_ = 0; n_ < 2; n_++) { \
        bF[(np)*2 + n_][0] = *(const u16x8*)((reg) + ((np)*2 + n_) * 2048 + lane0); \
        bF[(np)*2 + n_][1] = *(const u16x8*)((reg) + ((np)*2 + n_) * 2048 + lane1); \
    } } while (0)

#define MFMA8(ma, np) do { \
    __builtin_amdgcn_s_setprio(1); \
    _Pragma("unroll") \
    for (int m_ = 0; m_ < 4; m_++) \
        _Pragma("unroll") \
        for (int n_ = 0; n_ < 2; n_++) { \
            acc[(ma)+m_][(np)*2+n_] = mfma32(aF[m_][0], bF[(np)*2+n_][0], acc[(ma)+m_][(np)*2+n_]); \
            acc[(ma)+m_][(np)*2+n_] = mfma32(aF[m_][1], bF[(np)*2+n_][1], acc[(ma)+m_][(np)*2+n_]); \
        } \
    __builtin_amdgcn_s_setprio(0); \
} while (0)

// stage one 128x64 half-tile (2 x gld16). par/isB/h are literals at call sites.
#define STG(base, T, h, par, isB) do { \
    const unsigned short* s_ = (base) + (size_t)((h) * 128) * K + (size_t)(T) * 64; \
    unsigned short* d_ = dst0 + (par) * 32768 + (isB) * 16384 + (h) * 8192; \
    gld16(s_, d_); gld16(s_ + (size_t)64 * K, d_ + 4096); } while (0)

template<int MODE>
__global__ __launch_bounds__(512, 2) void gemm256(
    const unsigned short* __restrict__ A, const unsigned short* __restrict__ Bt,
    const float* __restrict__ bias, void* __restrict__ Cout, int N, int K)
{
    __shared__ unsigned short lds[65536] __attribute__((aligned(128)));
    const int tid = threadIdx.x, wid = tid >> 6, lane = tid & 63;
    const int l16 = lane & 15, lhi = lane >> 4;
    const int wr = wid >> 2, wc = wid & 3;

    int flat = blockIdx.x;
    { int cpx = gridDim.x >> 3; flat = (flat & 7) * cpx + (flat >> 3); }
    const int bm = flat & 15, bn = flat >> 4;
    const int NT = K >> 6;

    const int srowL = tid >> 3;                                      // 0..63
    const int scolb = ((tid & 7) << 4) ^ (((tid >> 3) & 7) << 4);    // bytes (pre-swizzled src)
    const unsigned short* baseA = A  + (size_t)(bm * 256 + srowL) * K + (scolb >> 1);
    const unsigned short* baseB = Bt + (size_t)(bn * 256 + srowL) * K + (scolb >> 1);
    unsigned short* dst0 = lds + wid * 512;   // wave-uniform; HW adds lane*16B

    const int lswz  = (l16 & 7) << 4;
    const int lane0 = ((lhi * 16) ^ lswz) + l16 * 128;
    const int lane1 = ((64 + lhi * 16) ^ lswz) + l16 * 128;

    const char* aR0 = (const char*)lds + wr * 16384;
    const char* bR0 = (const char*)lds + 32768 + (wc >> 1) * 16384 + (wc & 1) * 8192;
    const char* aR1 = aR0 + 65536;
    const char* bR1 = bR0 + 65536;

    f32x4 acc[8][4];
#pragma unroll
    for (int i = 0; i < 8; i++)
#pragma unroll
        for (int j = 0; j < 4; j++) acc[i][j] = (f32x4){0.f, 0.f, 0.f, 0.f};
    u16x8 aF[4][2], bF[4][2];

    // prologue: B(0),A(0),B(1); leave B(1)'s 4 loads in flight
    STG(baseB, 0, 0, 0, 1); STG(baseB, 0, 1, 0, 1);
    STG(baseA, 0, 0, 0, 0); STG(baseA, 0, 1, 0, 0);
    STG(baseB, 1, 0, 1, 1); STG(baseB, 1, 1, 1, 1);
    VM4();
    __builtin_amdgcn_s_barrier();

    int t = 0;
    for (; t + 2 < NT; t += 2) {
        // ---- K-tile t (buf0) ----
        LOADA(aR0, 0); LOADB(bR0, 0); STG(baseA, t + 1, 0, 1, 0);
        PSYNC(); MFMA8(0, 0); PEND();
        LOADB(bR0, 1);                STG(baseA, t + 1, 1, 1, 0);
        PSYNC(); MFMA8(0, 1); PEND();
        LOADA(aR0, 1);                STG(baseB, t + 2, 0, 0, 1);
        PSYNC(); MFMA8(4, 0); PEND();
                                      STG(baseB, t + 2, 1, 0, 1); VM4();
        PSYNC(); MFMA8(4, 1); PEND();
        // ---- K-tile t+1 (buf1) ----
        LOADA(aR1, 0); LOADB(bR1, 0); STG(baseA, t + 2, 0, 0, 0);
        PSYNC(); MFMA8(0, 0); PEND();
        LOADB(bR1, 1);                STG(baseA, t + 2, 1, 0, 0);
        PSYNC(); MFMA8(0, 1); PEND();
        LOADA(aR1, 1);                STG(baseB, t + 3, 0, 1, 1);
        PSYNC(); MFMA8(4, 0); PEND();
                                      STG(baseB, t + 3, 1, 1, 1); VM4();
        PSYNC(); MFMA8(4, 1); PEND();
    }
    // ---- epilogue: tiles t, t+1 ----
    LOADA(aR0, 0); LOADB(bR0, 0); STG(baseA, t + 1, 0, 1, 0);
    PSYNC(); MFMA8(0, 0); PEND();
    LOADB(bR0, 1);                STG(baseA, t + 1, 1, 1, 0);
    PSYNC(); MFMA8(0, 1); PEND();
    LOADA(aR0, 1);
    PSYNC(); MFMA8(4, 0); PEND();
    asm volatile("s_waitcnt vmcnt(0)" ::: "memory");
    PSYNC(); MFMA8(4, 1); PEND();
    LOADA(aR1, 0); LOADB(bR1, 0);
    PSYNC(); MFMA8(0, 0); PEND();
    LOADB(bR1, 1);
    PSYNC(); MFMA8(0, 1); PEND();
    LOADA(aR1, 1);
    PSYNC(); MFMA8(4, 0); PEND();
    PSYNC(); MFMA8(4, 1);

#pragma unroll
    for (int mi = 0; mi < 8; mi++)
#pragma unroll
        for (int ni = 0; ni < 4; ni++) {
            int row = bm * 256 + wr * 128 + mi * 16 + lhi * 4;
            int col = bn * 256 + wc * 64 + ni * 16 + l16;
            float bv = bias ? bias[col] : 0.f;
#pragma unroll
            for (int j = 0; j < 4; j++) {
                float v = acc[mi][ni][j] + bv;
                size_t idx = (size_t)(row + j) * N + col;
                if constexpr (MODE == 0) {
                    ((float*)Cout)[idx] = v;
                } else if constexpr (MODE == 1) {
                    ((unsigned short*)Cout)[idx] = f2bf(v);
                } else {
                    ((unsigned short*)Cout)[idx] = f2bf(v > 0.f ? v : 0.f);
                }
            }
        }
}

// ---------------- flash attention (causal), 64 q-rows/block, fused qkv input ----------------
__global__ __launch_bounds__(256, 3) void attn_fwd(
    const unsigned short* __restrict__ qkv, unsigned short* __restrict__ ctxb)
{
    __shared__ unsigned short Ks[64 * 72];
    __shared__ unsigned short Vs[64 * 72];   // transposed: Vs[d][kv]
    __shared__ unsigned short Ps[4 * 16 * 72];
    const int tid = threadIdx.x;
    const int wid = tid >> 6, lane = tid & 63;
    const int l16 = lane & 15, lhi = lane >> 4;
    const int bh  = blockIdx.y, b = bh >> 4, h = bh & 15;
    const int q0  = blockIdx.x * 64;
    const size_t rowbase = (size_t)b * SEQ;

    const int qrow = q0 + wid * 16 + l16;
    const unsigned short* qp = qkv + (rowbase + qrow) * QKV_N + h * HDIM + lhi * 8;
    u16x8 qf0 = *(const u16x8*)qp;
    u16x8 qf1 = *(const u16x8*)(qp + 32);

    f32x4 oa[4];
    float mj[4], lj[4];
#pragma unroll
    for (int i = 0; i < 4; i++) {
        oa[i] = (f32x4){0.f, 0.f, 0.f, 0.f};
        mj[i] = -1e30f; lj[i] = 0.f;
    }

    const int ntiles = blockIdx.x + 1;
    for (int kt = 0; kt < ntiles; ++kt) {
        const int kv0 = kt * 64;
        __syncthreads();
#pragma unroll
        for (int it = 0; it < 2; ++it) {
            int e = it * 256 + tid;
            int r = e >> 3, d0 = (e & 7) * 8;
            size_t goff = (rowbase + kv0 + r) * QKV_N + D_MODEL + h * HDIM + d0;
            u16x8 kk = *(const u16x8*)(qkv + goff);
            *(u16x8*)(&Ks[r * 72 + d0]) = kk;
            u16x8 vv = *(const u16x8*)(qkv + goff + D_MODEL);
#pragma unroll
            for (int j = 0; j < 8; j++) Vs[(d0 + j) * 72 + r] = vv[j];
        }
        __syncthreads();

        f32x4 sa[4];
#pragma unroll
        for (int ni = 0; ni < 4; ni++) {
            f32x4 z = (f32x4){0.f, 0.f, 0.f, 0.f};
            u16x8 k0f = *(const u16x8*)(&Ks[(ni * 16 + l16) * 72 + lhi * 8]);
            u16x8 k1f = *(const u16x8*)(&Ks[(ni * 16 + l16) * 72 + 32 + lhi * 8]);
            z = mfma32(qf0, k0f, z);
            z = mfma32(qf1, k1f, z);
            sa[ni] = z;
        }
        float tm[4] = {-1e30f, -1e30f, -1e30f, -1e30f};
#pragma unroll
        for (int ni = 0; ni < 4; ni++)
#pragma unroll
            for (int j = 0; j < 4; j++) {
                float v = sa[ni][j] * 0.125f;
                int row = q0 + wid * 16 + lhi * 4 + j;
                int col = kv0 + ni * 16 + l16;
                if (col > row) v = -1e30f;
                sa[ni][j] = v;
                tm[j] = fmaxf(tm[j], v);
            }
#pragma unroll
        for (int j = 0; j < 4; j++) {
#pragma unroll
            for (int off = 1; off < 16; off <<= 1)
                tm[j] = fmaxf(tm[j], __shfl_xor(tm[j], off));
        }
        float al[4], rs[4] = {0.f, 0.f, 0.f, 0.f};
#pragma unroll
        for (int j = 0; j < 4; j++) {
            float mn = fmaxf(mj[j], tm[j]);
            al[j] = __expf(mj[j] - mn);
            mj[j] = mn;
        }
#pragma unroll
        for (int ni = 0; ni < 4; ni++)
#pragma unroll
            for (int j = 0; j < 4; j++) {
                float p = __expf(sa[ni][j] - mj[j]);
                rs[j] += p;
                Ps[wid * 1152 + (lhi * 4 + j) * 72 + ni * 16 + l16] = f2bf(p);
            }
#pragma unroll
        for (int j = 0; j < 4; j++) {
#pragma unroll
            for (int off = 1; off < 16; off <<= 1)
                rs[j] += __shfl_xor(rs[j], off);
            lj[j] = lj[j] * al[j] + rs[j];
        }
#pragma unroll
        for (int di = 0; di < 4; di++)
#pragma unroll
            for (int j = 0; j < 4; j++) oa[di][j] *= al[j];
#pragma unroll
        for (int di = 0; di < 4; di++) {
#pragma unroll
            for (int kc = 0; kc < 2; kc++) {
                u16x8 pf = *(const u16x8*)(&Ps[wid * 1152 + l16 * 72 + kc * 32 + lhi * 8]);
                u16x8 vf = *(const u16x8*)(&Vs[(di * 16 + l16) * 72 + kc * 32 + lhi * 8]);
                oa[di] = mfma32(pf, vf, oa[di]);
            }
        }
    }
#pragma unroll
    for (int di = 0; di < 4; di++)
#pragma unroll
        for (int j = 0; j < 4; j++) {
            int row = q0 + wid * 16 + lhi * 4 + j;
            ctxb[(rowbase + row) * D_MODEL + h * HDIM + di * 16 + l16] =
                f2bf(oa[di][j] / lj[j]);
        }
}

// ---------------- fused residual(x + p0 + p1) + LayerNorm ----------------
__global__ __launch_bounds__(256) void ln3(
    float* __restrict__ x, const float* __restrict__ p0, const float* __restrict__ p1,
    const float* __restrict__ sc, const float* __restrict__ bi,
    unsigned short* __restrict__ xb)
{
    const int row = blockIdx.x;
    const int t = threadIdx.x;
    const size_t base = (size_t)row * D_MODEL + t * 4;
    float4 xv = *(const float4*)(x + base);
    float4 av = *(const float4*)(p0 + base);
    float4 bvv = *(const float4*)(p1 + base);
    float v0 = xv.x + av.x + bvv.x, v1 = xv.y + av.y + bvv.y;
    float v2 = xv.z + av.z + bvv.z, v3 = xv.w + av.w + bvv.w;
    float sum = v0 + v1 + v2 + v3;
    float sq  = v0 * v0 + v1 * v1 + v2 * v2 + v3 * v3;
#pragma unroll
    for (int off = 1; off < 64; off <<= 1) {
        sum += __shfl_xor(sum, off);
        sq  += __shfl_xor(sq, off);
    }
    __shared__ float red[8];
    int wid = t >> 6, lane = t & 63;
    if (lane == 0) { red[wid] = sum; red[4 + wid] = sq; }
    __syncthreads();
    sum = red[0] + red[1] + red[2] + red[3];
    sq  = red[4] + red[5] + red[6] + red[7];
    float mu   = sum * (1.f / D_MODEL);
    float var  = sq * (1.f / D_MODEL) - mu * mu;
    float rstd = rsqrtf(var + LN_EPS);
    int c = t * 4;
    float4 sv = *(const float4*)(sc + c);
    float4 bv = *(const float4*)(bi + c);
    float y0 = sv.x * (v0 - mu) * rstd + bv.x;
    float y1 = sv.y * (v1 - mu) * rstd + bv.y;
    float y2 = sv.z * (v2 - mu) * rstd + bv.z;
    float y3 = sv.w * (v3 - mu) * rstd + bv.w;
    *(float4*)(x + base) = make_float4(y0, y1, y2, y3);
    unsigned long long pk = (unsigned long long)f2bf(y0)
        | ((unsigned long long)f2bf(y1) << 16)
        | ((unsigned long long)f2bf(y2) << 32)
        | ((unsigned long long)f2bf(y3) << 48);
    *(unsigned long long*)(xb + base) = pk;
}

// ---------------- launcher ----------------
extern "C" void kernel_launch(void* const* d_in, const int* in_sizes, int n_in,
                              void* d_out, int out_size, void* d_ws, size_t ws_size,
                              hipStream_t stream)
{
    (void)in_sizes; (void)n_in; (void)out_size;
    const int*   tokens = (const int*)d_in[0];
    const float* emb  = (const float*)d_in[2];
    const float* pose = (const float*)d_in[3];
    const float* Wq = (const float*)d_in[4];
    const float* bq = (const float*)d_in[5];
    const float* Wk = (const float*)d_in[6];
    const float* bk = (const float*)d_in[7];
    const float* Wv = (const float*)d_in[8];
    const float* bv = (const float*)d_in[9];
    const float* Wo = (const float*)d_in[10];
    const float* bo = (const float*)d_in[11];
    const float* n1s = (const float*)d_in[12];
    const float* n1b = (const float*)d_in[13];
    const float* W1 = (const float*)d_in[14];
    const float* b1 = (const float*)d_in[15];
    const float* W2 = (const float*)d_in[16];
    const float* b2 = (const float*)d_in[17];
    const float* n2s = (const float*)d_in[18];
    const float* n2b = (const float*)d_in[19];

    char* w = (char*)d_ws;
    size_t off = 0;
    auto carve = [&](size_t bytes) -> void* {
        void* p = w + off;
        off = (off + bytes + 255) & ~(size_t)255;
        return p;
    };
    float* x   = (float*)carve((size_t)ROWS * D_MODEL * 4);
    float* tmp = (float*)carve((size_t)2 * ROWS * D_MODEL * 4);   // 2 split-K partials
    unsigned short* xb    = (unsigned short*)carve((size_t)ROWS * D_MODEL * 2);
    unsigned short* qkvb  = (unsigned short*)carve((size_t)ROWS * QKV_N * 2);
    unsigned short* cbuf  = (unsigned short*)carve((size_t)ROWS * D_MODEL * 2);
    unsigned short* hbuf  = (unsigned short*)carve((size_t)ROWS * FF_DIM * 2);
    unsigned short* wt    = (unsigned short*)carve((size_t)D_MODEL * FF_DIM * 2);
    float* bqkv = (float*)carve((size_t)NLAYER * QKV_N * 4);
    unsigned short* embb = qkvb;   // tied-head emb aliases dead qkv/ctx/h(+wt) region
    float* tmp1 = tmp + (size_t)ROWS * D_MODEL;
    if (off > ws_size) return;

    bias3_k<<<NLAYER * 3, 256, 0, stream>>>(bq, bk, bv, bqkv);
    embed_k<<<ROWS, 256, 0, stream>>>(tokens, emb, pose, x, xb);

    for (int l = 0; l < NLAYER; l++) {
        const float* Wq_l = Wq + (size_t)l * D_MODEL * D_MODEL;
        const float* Wk_l = Wk + (size_t)l * D_MODEL * D_MODEL;
        const float* Wv_l = Wv + (size_t)l * D_MODEL * D_MODEL;
        const float* Wo_l = Wo + (size_t)l * D_MODEL * D_MODEL;
        const float* W1_l = W1 + (size_t)l * D_MODEL * FF_DIM;
        const float* W2_l = W2 + (size_t)l * FF_DIM * D_MODEL;

        transpose_cast<<<dim3(16, 16), 256, 0, stream>>>(Wq_l, wt, D_MODEL, D_MODEL);
        transpose_cast<<<dim3(16, 16), 256, 0, stream>>>(Wk_l, wt + 1024 * 1024, D_MODEL, D_MODEL);
        transpose_cast<<<dim3(16, 16), 256, 0, stream>>>(Wv_l, wt + 2 * 1024 * 1024, D_MODEL, D_MODEL);
        gemm256<1><<<(QKV_N / 256) * 16, 512, 0, stream>>>(xb, wt, bqkv + (size_t)l * QKV_N, qkvb, QKV_N, D_MODEL);

        attn_fwd<<<dim3(SEQ / 64, BATCH * NHEAD), 256, 0, stream>>>(qkvb, cbuf);

        transpose_cast<<<dim3(16, 16), 256, 0, stream>>>(Wo_l, wt, D_MODEL, D_MODEL);
        gemm_bt<0><<<dim3(256, 2), 256, 0, stream>>>(cbuf, D_MODEL, wt, D_MODEL,
                                                     bo + (size_t)l * D_MODEL, tmp, D_MODEL, D_MODEL / 2);
        ln3<<<ROWS, 256, 0, stream>>>(x, tmp, tmp1, n1s + (size_t)l * D_MODEL, n1b + (size_t)l * D_MODEL, xb);

        transpose_cast<<<dim3(64, 16), 256, 0, stream>>>(W1_l, wt, D_MODEL, FF_DIM);
        gemm256<2><<<(FF_DIM / 256) * 16, 512, 0, stream>>>(xb, wt, b1 + (size_t)l * FF_DIM, hbuf, FF_DIM, D_MODEL);
        transpose_cast<<<dim3(16, 64), 256, 0, stream>>>(W2_l, wt, FF_DIM, D_MODEL);
        gemm_bt<0><<<dim3(256, 2), 256, 0, stream>>>(hbuf, FF_DIM, wt, FF_DIM,
                                                     b2 + (size_t)l * D_MODEL, tmp, D_MODEL, FF_DIM / 2);
        ln3<<<ROWS, 256, 0, stream>>>(x, tmp, tmp1, n2s + (size_t)l * D_MODEL, n2b + (size_t)l * D_MODEL, xb);
    }

    cast_bf<<<(VOCAB * D_MODEL) / 1024, 256, 0, stream>>>(emb, embb, (size_t)VOCAB * D_MODEL);
    gemm256<0><<<(VOCAB / 256) * 16, 512, 0, stream>>>(xb, embb, nullptr, d_out, VOCAB, D_MODEL);
}